// Round 1
// baseline (605.798 us; speedup 1.0000x reference)
//
#include <hip/hip_runtime.h>
#include <math.h>

// 1/sqrt(1+1e-5) in fp32
#define BN_INV_F 0.9999950000374997f

// ---------------------------------------------------------------------------
// Generic direct 3x3 conv, pad=1, square images.
//   - optional per-(b,cin) input scale (SE scale of previous block)
//   - epilogue: BN(gamma*BN_INV, beta)+ReLU  (BN_RELU=true)  or  +bias (false)
//   - optional per-(b,cout) spatial sum accumulation for SE (SE_SUM)
// Thread = one output pixel, computes COB output channels (one cout group).
// grid = (HOUT*HOUT/256, COUT/COB, B), block = 256
// ---------------------------------------------------------------------------
template <int CIN, int COUT, int COB, int HIN, int HOUT, int STRIDE,
          bool BN_RELU, bool SE_SUM>
__global__ __launch_bounds__(256) void conv3x3_k(
    const float* __restrict__ in, const float* __restrict__ w,
    const float* __restrict__ scale_in,  // per (b,cin), may be nullptr
    const float* __restrict__ gamma,     // BN gamma (BN_RELU) or bias
    const float* __restrict__ beta,      // BN beta  (BN_RELU) or unused
    float* __restrict__ out,
    float* __restrict__ se_sum)          // per (b,cout) sums (SE_SUM)
{
    constexpr int WIN = HIN, WOUT = HOUT;
    const int b = blockIdx.z;
    const int g = blockIdx.y;  // cout group
    const int sp = blockIdx.x * 256 + threadIdx.x;
    const int ho = sp / WOUT, wo = sp % WOUT;

    __shared__ float wl[CIN * 9 * COB];
    __shared__ float scl[CIN];
    __shared__ float gl[COB];
    __shared__ float bl[COB];
    __shared__ float red[4][COB];

    // stage weights: wl[(cin*9+k)*COB + co_l] = w[(co)(cin)(k)]
    for (int t = threadIdx.x; t < CIN * 9 * COB; t += 256) {
        int col = t % COB;
        int rk = t / COB;            // cin*9 + k
        int cin = rk / 9, k = rk % 9;
        int co = g * COB + col;
        wl[t] = w[((size_t)co * CIN + cin) * 9 + k];
    }
    for (int t = threadIdx.x; t < CIN; t += 256)
        scl[t] = scale_in ? scale_in[b * CIN + t] : 1.0f;
    if (threadIdx.x < COB) {
        int co = g * COB + threadIdx.x;
        if (BN_RELU) {
            gl[threadIdx.x] = gamma[co] * BN_INV_F;
            bl[threadIdx.x] = beta[co];
        } else {
            gl[threadIdx.x] = gamma[co];  // bias
        }
    }
    __syncthreads();

    float acc[COB];
#pragma unroll
    for (int i = 0; i < COB; i++) acc[i] = 0.0f;

    const float* inb = in + (size_t)b * CIN * HIN * WIN;
#pragma unroll 1
    for (int cin = 0; cin < CIN; ++cin) {
        const float s = scl[cin];
        const float* inc = inb + (size_t)cin * HIN * WIN;
#pragma unroll
        for (int kh = 0; kh < 3; ++kh) {
            const int hi = ho * STRIDE - 1 + kh;
#pragma unroll
            for (int kw = 0; kw < 3; ++kw) {
                const int wi = wo * STRIDE - 1 + kw;
                float v = 0.0f;
                if (hi >= 0 && hi < HIN && wi >= 0 && wi < WIN)
                    v = inc[hi * WIN + wi] * s;
                const float* wrow = &wl[(cin * 9 + kh * 3 + kw) * COB];
#pragma unroll
                for (int co = 0; co < COB; co++)
                    acc[co] = fmaf(wrow[co], v, acc[co]);
            }
        }
    }

    // epilogue
    float* outb = out + ((size_t)b * COUT + g * COB) * HOUT * WOUT + sp;
#pragma unroll
    for (int co = 0; co < COB; co++) {
        float v;
        if (BN_RELU) {
            v = fmaxf(fmaf(acc[co], gl[co], bl[co]), 0.0f);
        } else {
            v = acc[co] + gl[co];
        }
        acc[co] = v;
        outb[(size_t)co * HOUT * WOUT] = v;
    }

    if (SE_SUM) {
        const int lane = threadIdx.x & 63, wv = threadIdx.x >> 6;
#pragma unroll
        for (int co = 0; co < COB; co++) {
            float v = acc[co];
            for (int off = 32; off; off >>= 1) v += __shfl_down(v, off, 64);
            if (lane == 0) red[wv][co] = v;
        }
        __syncthreads();
        if (threadIdx.x < COB) {
            float v = red[0][threadIdx.x] + red[1][threadIdx.x] +
                      red[2][threadIdx.x] + red[3][threadIdx.x];
            atomicAdd(&se_sum[b * COUT + g * COB + threadIdx.x], v);
        }
    }
}

// ---------------------------------------------------------------------------
// SE MLP: scale[b][c] = sigmoid( relu(mean . w1^T + b1) . w2^T + b2 )
// grid = B, block = 64 (C <= 64)
// ---------------------------------------------------------------------------
template <int C, int H, int SPATIAL>
__global__ void se_scale_k(const float* __restrict__ sums,
                           const float* __restrict__ w1,
                           const float* __restrict__ b1,
                           const float* __restrict__ w2,
                           const float* __restrict__ b2,
                           float* __restrict__ scale)
{
    const int b = blockIdx.x;
    __shared__ float mean[C];
    __shared__ float hid[H];
    if (threadIdx.x < C)
        mean[threadIdx.x] = sums[b * C + threadIdx.x] * (1.0f / (float)SPATIAL);
    __syncthreads();
    if (threadIdx.x < H) {
        float a = b1[threadIdx.x];
        for (int c = 0; c < C; c++) a = fmaf(mean[c], w1[threadIdx.x * C + c], a);
        hid[threadIdx.x] = fmaxf(a, 0.0f);
    }
    __syncthreads();
    if (threadIdx.x < C) {
        float a = b2[threadIdx.x];
        for (int h = 0; h < H; h++) a = fmaf(hid[h], w2[threadIdx.x * H + h], a);
        scale[b * C + threadIdx.x] = 1.0f / (1.0f + expf(-a));
    }
}

// ---------------------------------------------------------------------------
// Capsule squash. u_raw: (B,64,16,16) NCHW.  capsule i = (c>>3)*256 + h*16 + w,
// component j = c&7.  u out: (B,2048,8) contiguous.
// ---------------------------------------------------------------------------
__global__ __launch_bounds__(256) void squash_k(const float* __restrict__ u_raw,
                                                float* __restrict__ u)
{
    const int idx = blockIdx.x * 256 + threadIdx.x;  // b*2048 + i
    const int b = idx >> 11, i = idx & 2047;
    const int chi = i >> 8, spx = i & 255;
    const float* p = u_raw + ((size_t)(b * 64 + chi * 8)) * 256 + spx;
    float s[8];
    float n2 = 0.0f;
#pragma unroll
    for (int j = 0; j < 8; j++) {
        s[j] = p[(size_t)j * 256];
        n2 = fmaf(s[j], s[j], n2);
    }
    const float n = sqrtf(n2);
    const float f = (n2 / (1.0f + n2)) / (n + 1e-8f);
    float* q = u + (size_t)idx * 8;
#pragma unroll
    for (int j = 0; j < 8; j++) q[j] = s[j] * f;
}

// ---------------------------------------------------------------------------
// u_hat[b,i,c,d] = sum_e W[i,c,d,e] * u[b,i,e]   (cd = c*16+d in [0,48))
// ---------------------------------------------------------------------------
__global__ __launch_bounds__(256) void uhat_k(const float* __restrict__ u,
                                              const float* __restrict__ W,
                                              float* __restrict__ u_hat)
{
    const int idx = blockIdx.x * 256 + threadIdx.x;  // (b*2048+i)*48 + cd
    const int cd = idx % 48;
    const int bi = idx / 48;
    const int i = bi & 2047;
    const float* uu = u + (size_t)bi * 8;
    const float* wp = W + (size_t)i * 384 + cd * 8;
    float a = 0.0f;
#pragma unroll
    for (int e = 0; e < 8; e++) a = fmaf(wp[e], uu[e], a);
    u_hat[idx] = a;
}

// ---------------------------------------------------------------------------
// Dynamic routing, 3 iterations, one block per batch element.
// b_ij kept in LDS (2048*3 floats). u_hat re-read from L2 each pass.
// out[b][c] = || v_j[c] ||
// ---------------------------------------------------------------------------
__global__ __launch_bounds__(256) void routing_k(const float* __restrict__ u_hat,
                                                 float* __restrict__ out)
{
    const int b = blockIdx.x;
    const int tid = threadIdx.x;
    __shared__ float blds[2048 * 3];
    __shared__ float red[4][48];
    __shared__ float vsh[48];
    __shared__ float fac[3];

    for (int t = tid; t < 2048 * 3; t += 256) blds[t] = 0.0f;
    __syncthreads();

    const float* uh_b = u_hat + (size_t)b * 2048 * 48;

    for (int it = 0; it < 3; ++it) {
        float sp[48];
#pragma unroll
        for (int j = 0; j < 48; j++) sp[j] = 0.0f;

        for (int k = 0; k < 8; k++) {
            const int i = tid + k * 256;
            float b0 = blds[i * 3 + 0], b1 = blds[i * 3 + 1], b2 = blds[i * 3 + 2];
            float m = fmaxf(b0, fmaxf(b1, b2));
            float e0 = expf(b0 - m), e1 = expf(b1 - m), e2 = expf(b2 - m);
            float inv = 1.0f / (e0 + e1 + e2);
            float c0 = e0 * inv, c1 = e1 * inv, c2 = e2 * inv;
            const float* uh = uh_b + (size_t)i * 48;
#pragma unroll
            for (int d = 0; d < 16; d++) {
                sp[d]      = fmaf(c0, uh[d],      sp[d]);
                sp[16 + d] = fmaf(c1, uh[16 + d], sp[16 + d]);
                sp[32 + d] = fmaf(c2, uh[32 + d], sp[32 + d]);
            }
        }

        // reduce sp[48] across 256 threads
        const int lane = tid & 63, wv = tid >> 6;
#pragma unroll
        for (int j = 0; j < 48; j++) {
            float x = sp[j];
            for (int off = 32; off; off >>= 1) x += __shfl_down(x, off, 64);
            if (lane == 0) red[wv][j] = x;
        }
        __syncthreads();
        if (tid < 48)
            vsh[tid] = red[0][tid] + red[1][tid] + red[2][tid] + red[3][tid];
        __syncthreads();
        if (tid < 3) {
            float n2 = 0.0f;
            for (int d = 0; d < 16; d++) n2 = fmaf(vsh[tid * 16 + d], vsh[tid * 16 + d], n2);
            float n = sqrtf(n2);
            fac[tid] = (n2 / (1.0f + n2)) / (n + 1e-8f);
        }
        __syncthreads();
        if (tid < 48) vsh[tid] = vsh[tid] * fac[tid / 16];
        __syncthreads();

        if (it < 2) {
            for (int k = 0; k < 8; k++) {
                const int i = tid + k * 256;
                const float* uh = uh_b + (size_t)i * 48;
                float a0 = 0.0f, a1 = 0.0f, a2 = 0.0f;
#pragma unroll
                for (int d = 0; d < 16; d++) {
                    a0 = fmaf(uh[d],      vsh[d],      a0);
                    a1 = fmaf(uh[16 + d], vsh[16 + d], a1);
                    a2 = fmaf(uh[32 + d], vsh[32 + d], a2);
                }
                blds[i * 3 + 0] += a0;
                blds[i * 3 + 1] += a1;
                blds[i * 3 + 2] += a2;
            }
            __syncthreads();
        }
    }

    if (tid < 3) {
        float n2 = 0.0f;
        for (int d = 0; d < 16; d++) n2 = fmaf(vsh[tid * 16 + d], vsh[tid * 16 + d], n2);
        out[b * 3 + tid] = sqrtf(n2);
    }
}

// ---------------------------------------------------------------------------
extern "C" void kernel_launch(void* const* d_in, const int* in_sizes, int n_in,
                              void* d_out, int out_size, void* d_ws, size_t ws_size,
                              hipStream_t stream)
{
    const float* x       = (const float*)d_in[0];
    const float* conv1_w = (const float*)d_in[1];
    const float* bn1_g   = (const float*)d_in[2];
    const float* bn1_b   = (const float*)d_in[3];
    const float* se1_w1  = (const float*)d_in[4];
    const float* se1_b1  = (const float*)d_in[5];
    const float* se1_w2  = (const float*)d_in[6];
    const float* se1_b2  = (const float*)d_in[7];
    const float* conv2_w = (const float*)d_in[8];
    const float* bn2_g   = (const float*)d_in[9];
    const float* bn2_b   = (const float*)d_in[10];
    const float* se2_w1  = (const float*)d_in[11];
    const float* se2_b1  = (const float*)d_in[12];
    const float* se2_w2  = (const float*)d_in[13];
    const float* se2_b2  = (const float*)d_in[14];
    const float* conv3_w = (const float*)d_in[15];
    const float* bn3_g   = (const float*)d_in[16];
    const float* bn3_b   = (const float*)d_in[17];
    const float* se3_w1  = (const float*)d_in[18];
    const float* se3_b1  = (const float*)d_in[19];
    const float* se3_w2  = (const float*)d_in[20];
    const float* se3_b2  = (const float*)d_in[21];
    const float* pc_w    = (const float*)d_in[22];
    const float* pc_b    = (const float*)d_in[23];
    const float* W_digit = (const float*)d_in[24];  // (1,2048,3,16,8)

    float* ws = (float*)d_ws;
    // layout (floats):
    //   [0 .. 16777216)          h1 (64,16,128,128); later reused:
    //       [0 .. 4194304)       h3 (64,64,32,32)
    //       [4194304 .. 5242880) u_raw (64,64,16,16)
    //       [5242880 .. 6291456) u (64,2048,8)
    //       [6291456 .. 12582912) u_hat (64,2048,48)
    //   [16777216 .. 25165824)   h2 (64,32,64,64)
    //   [25165824 .. +7168)      SE sums  [s1 1024][s2 2048][s3 4096]
    //   [.. +7168)               SE scales
    float* h1    = ws;
    float* h2    = ws + 16777216;
    float* h3    = ws;
    float* u_raw = ws + 4194304;
    float* u     = ws + 5242880;
    float* u_hat = ws + 6291456;
    float* sums  = ws + 25165824;
    float* scls  = sums + 7168;
    float* s1 = sums,        *s2 = sums + 1024, *s3 = sums + 3072;
    float* sc1 = scls,       *sc2 = scls + 1024, *sc3 = scls + 3072;

    hipMemsetAsync(sums, 0, 7168 * sizeof(float), stream);

    // block 1: conv(1->16, 128x128, s1) + BN + ReLU, SE sums
    conv3x3_k<1, 16, 16, 128, 128, 1, true, true>
        <<<dim3(64, 1, 64), 256, 0, stream>>>(x, conv1_w, nullptr, bn1_g, bn1_b, h1, s1);
    se_scale_k<16, 1, 16384><<<64, 64, 0, stream>>>(s1, se1_w1, se1_b1, se1_w2, se1_b2, sc1);

    // block 2: conv(16->32, ->64x64, s2)
    conv3x3_k<16, 32, 32, 128, 64, 2, true, true>
        <<<dim3(16, 1, 64), 256, 0, stream>>>(h1, conv2_w, sc1, bn2_g, bn2_b, h2, s2);
    se_scale_k<32, 2, 4096><<<64, 64, 0, stream>>>(s2, se2_w1, se2_b1, se2_w2, se2_b2, sc2);

    // block 3: conv(32->64, ->32x32, s2)
    conv3x3_k<32, 64, 32, 64, 32, 2, true, true>
        <<<dim3(4, 2, 64), 256, 0, stream>>>(h2, conv3_w, sc2, bn3_g, bn3_b, h3, s3);
    se_scale_k<64, 4, 1024><<<64, 64, 0, stream>>>(s3, se3_w1, se3_b1, se3_w2, se3_b2, sc3);

    // primary caps conv(64->64, ->16x16, s2) + bias (SE3 scale folded into input)
    conv3x3_k<64, 64, 16, 32, 16, 2, false, false>
        <<<dim3(1, 4, 64), 256, 0, stream>>>(h3, pc_w, sc3, pc_b, nullptr, u_raw, nullptr);

    // squash -> u (B,2048,8)
    squash_k<<<512, 256, 0, stream>>>(u_raw, u);

    // u_hat (B,2048,3,16)
    uhat_k<<<24576, 256, 0, stream>>>(u, W_digit, u_hat);

    // routing -> out (B,3)
    routing_k<<<64, 256, 0, stream>>>(u_hat, (float*)d_out);
}

// Round 2
// 518.491 us; speedup vs baseline: 1.1684x; 1.1684x over previous
//
#include <hip/hip_runtime.h>
#include <math.h>

#define BN_INV_F 0.9999950000374997f

// ---------------------------------------------------------------------------
// LDS-staged tiled direct 3x3 conv, pad=1.
//  - input tile (zero-padded) staged to LDS per CB-channel chunk; SE scale of
//    the PREVIOUS block folded in at staging time
//  - optional in-kernel SE-MLP (HSE_IN>0): scl = sigmoid(relu(mean.W1+b1).W2+b2)
//  - epilogue: BN+ReLU (BN_RELU) or +bias; optional per-(b,cout) SE sums
// Block: NTHREADS = TW * ROWS_T threads; thread owns PPT pixels (rows
// rg + p*ROWS_T within the tile), computes COB output channels.
// grid = (HOUT/(ROWS_T*PPT), COUT/COB, B)
// ---------------------------------------------------------------------------
template <int CIN, int COUT, int COB, int HIN, int HOUT, int STRIDE,
          int TW, int ROWS_T, int PPT, int CB, int NTHREADS,
          bool BN_RELU, bool SE_SUM, int HSE_IN>
__global__ __launch_bounds__(NTHREADS) void convt_k(
    const float* __restrict__ in, const float* __restrict__ w,
    const float* __restrict__ gamma,     // BN gamma (BN_RELU) or bias
    const float* __restrict__ beta,      // BN beta  (BN_RELU) or unused
    float* __restrict__ out,
    float* __restrict__ se_sum,          // out: per (b,cout) sums (SE_SUM)
    const float* __restrict__ se_sums_in,// in: prev-block sums (HSE_IN>0)
    const float* __restrict__ se_w1, const float* __restrict__ se_b1,
    const float* __restrict__ se_w2, const float* __restrict__ se_b2,
    float inv_spatial)
{
    constexpr int WIN = HIN, WOUT = HOUT;
    constexpr int TH = ROWS_T * PPT;
    constexpr int IH_T = (TH - 1) * STRIDE + 3;
    constexpr int IW_T = (TW - 1) * STRIDE + 3;
    constexpr int NW = NTHREADS / 64;
    static_assert(NTHREADS == TW * ROWS_T, "geometry");

    const int b = blockIdx.z;
    const int g = blockIdx.y;
    const int ty = blockIdx.x;
    const int tid = threadIdx.x;
    const int wo = tid % TW;
    const int rg = tid / TW;

    __shared__ float wl[CIN * 9 * COB];
    __shared__ float in_t[CB][IH_T][IW_T];
    __shared__ float scl[CIN];
    __shared__ float gl[COB], bl[COB];
    __shared__ float red[NW][COB];
    __shared__ float hid[HSE_IN > 0 ? HSE_IN : 1];

    // stage weights: wl[(cin*9+k)*COB + col]
    for (int t = tid; t < CIN * 9 * COB; t += NTHREADS) {
        int col = t % COB;
        int rk = t / COB;
        int cin = rk / 9, k = rk % 9;
        wl[t] = w[((size_t)(g * COB + col) * CIN + cin) * 9 + k];
    }
    if (tid < COB) {
        int co = g * COB + tid;
        if (BN_RELU) {
            gl[tid] = gamma[co] * BN_INV_F;
            bl[tid] = beta[co];
        } else {
            gl[tid] = gamma[co];
        }
    }
    // input SE scale (previous block) computed in-kernel
    if (HSE_IN > 0) {
        if (tid < HSE_IN) {
            float a = se_b1[tid];
            for (int c = 0; c < CIN; ++c)
                a = fmaf(se_sums_in[b * CIN + c] * inv_spatial, se_w1[tid * CIN + c], a);
            hid[tid] = fmaxf(a, 0.0f);
        }
        __syncthreads();
        if (tid < CIN) {
            float a = se_b2[tid];
            for (int h = 0; h < HSE_IN; ++h)
                a = fmaf(hid[h], se_w2[tid * HSE_IN + h], a);
            scl[tid] = 1.0f / (1.0f + expf(-a));
        }
    } else {
        for (int t = tid; t < CIN; t += NTHREADS) scl[t] = 1.0f;
    }

    float acc[PPT][COB];
#pragma unroll
    for (int p = 0; p < PPT; ++p)
#pragma unroll
        for (int co = 0; co < COB; ++co) acc[p][co] = 0.0f;

    const float* inb = in + (size_t)b * CIN * HIN * WIN;
    const int gr0 = ty * TH * STRIDE - 1;
    const int wos = wo * STRIDE;

    for (int cb0 = 0; cb0 < CIN; cb0 += CB) {
        __syncthreads();  // previous chunk's compute done (also covers wl/scl on iter 0)
        for (int idx = tid; idx < CB * IH_T * IW_T; idx += NTHREADS) {
            int ci = idx / (IH_T * IW_T);
            int rem = idx % (IH_T * IW_T);
            int lr = rem / IW_T, lc = rem % IW_T;
            int gr = gr0 + lr, gc = lc - 1;
            float v = 0.0f;
            if (gr >= 0 && gr < HIN && gc >= 0 && gc < WIN)
                v = inb[(size_t)(cb0 + ci) * HIN * WIN + gr * WIN + gc] * scl[cb0 + ci];
            in_t[ci][lr][lc] = v;
        }
        __syncthreads();

        for (int ci = 0; ci < CB; ++ci) {
#pragma unroll
            for (int kh = 0; kh < 3; ++kh) {
#pragma unroll
                for (int kw = 0; kw < 3; ++kw) {
                    const float* wrow = &wl[((cb0 + ci) * 9 + kh * 3 + kw) * COB];
                    float wv[COB];
#pragma unroll
                    for (int co = 0; co < COB; ++co) wv[co] = wrow[co];
#pragma unroll
                    for (int p = 0; p < PPT; ++p) {
                        float v = in_t[ci][(rg + p * ROWS_T) * STRIDE + kh][wos + kw];
#pragma unroll
                        for (int co = 0; co < COB; ++co)
                            acc[p][co] = fmaf(wv[co], v, acc[p][co]);
                    }
                }
            }
        }
    }

    // epilogue
    float tsum[COB];
#pragma unroll
    for (int co = 0; co < COB; ++co) tsum[co] = 0.0f;
    float* outb = out + ((size_t)b * COUT + g * COB) * HOUT * WOUT;
#pragma unroll
    for (int p = 0; p < PPT; ++p) {
        const int ho = ty * TH + rg + p * ROWS_T;
#pragma unroll
        for (int co = 0; co < COB; ++co) {
            float v;
            if (BN_RELU)
                v = fmaxf(fmaf(acc[p][co], gl[co], bl[co]), 0.0f);
            else
                v = acc[p][co] + gl[co];
            outb[(size_t)co * HOUT * WOUT + ho * WOUT + wo] = v;
            tsum[co] += v;
        }
    }

    if (SE_SUM) {
        const int lane = tid & 63, wv = tid >> 6;
#pragma unroll
        for (int co = 0; co < COB; ++co) {
            float v = tsum[co];
            for (int off = 32; off; off >>= 1) v += __shfl_down(v, off, 64);
            if (lane == 0) red[wv][co] = v;
        }
        __syncthreads();
        if (tid < COB) {
            float v = 0.0f;
#pragma unroll
            for (int k = 0; k < NW; ++k) v += red[k][tid];
            atomicAdd(&se_sum[b * COUT + g * COB + tid], v);
        }
    }
}

// ---------------------------------------------------------------------------
// Capsule squash. u_raw: (B,64,16,16) NCHW. cap i = (c>>3)*256 + h*16 + w,
// component j = c&7. u out: (B,2048,8).
// ---------------------------------------------------------------------------
__global__ __launch_bounds__(256) void squash_k(const float* __restrict__ u_raw,
                                                float* __restrict__ u)
{
    const int idx = blockIdx.x * 256 + threadIdx.x;  // b*2048 + i
    const int b = idx >> 11, i = idx & 2047;
    const int chi = i >> 8, spx = i & 255;
    const float* p = u_raw + ((size_t)(b * 64 + chi * 8)) * 256 + spx;
    float s[8];
    float n2 = 0.0f;
#pragma unroll
    for (int j = 0; j < 8; j++) {
        s[j] = p[(size_t)j * 256];
        n2 = fmaf(s[j], s[j], n2);
    }
    const float n = sqrtf(n2);
    const float f = (n2 / (1.0f + n2)) / (n + 1e-8f);
    float* q = u + (size_t)idx * 8;
#pragma unroll
    for (int j = 0; j < 8; j++) q[j] = s[j] * f;
}

// ---------------------------------------------------------------------------
// u_hat[b,i,c,d] = sum_e W[i,c,d,e] * u[b,i,e]
// ---------------------------------------------------------------------------
__global__ __launch_bounds__(256) void uhat_k(const float* __restrict__ u,
                                              const float* __restrict__ W,
                                              float* __restrict__ u_hat)
{
    const int idx = blockIdx.x * 256 + threadIdx.x;  // (b*2048+i)*48 + cd
    const int cd = idx % 48;
    const int bi = idx / 48;
    const int i = bi & 2047;
    const float* uu = u + (size_t)bi * 8;
    const float* wp = W + (size_t)i * 384 + cd * 8;
    float a = 0.0f;
#pragma unroll
    for (int e = 0; e < 8; e++) a = fmaf(wp[e], uu[e], a);
    u_hat[idx] = a;
}

// ---------------------------------------------------------------------------
// Dynamic routing, 3 iters, one 1024-thread block per batch element.
// ---------------------------------------------------------------------------
__global__ __launch_bounds__(1024) void routing_k(const float* __restrict__ u_hat,
                                                  float* __restrict__ out)
{
    const int b = blockIdx.x;
    const int tid = threadIdx.x;
    __shared__ float blds[2048 * 3];
    __shared__ float red[16][48];
    __shared__ float vsh[48];
    __shared__ float fac[3];

    for (int t = tid; t < 2048 * 3; t += 1024) blds[t] = 0.0f;
    __syncthreads();

    const float* uh_b = u_hat + (size_t)b * 2048 * 48;

    for (int it = 0; it < 3; ++it) {
        float sp[48];
#pragma unroll
        for (int j = 0; j < 48; j++) sp[j] = 0.0f;

#pragma unroll
        for (int k = 0; k < 2; k++) {
            const int i = tid + k * 1024;
            float b0 = blds[i * 3 + 0], b1 = blds[i * 3 + 1], b2 = blds[i * 3 + 2];
            float m = fmaxf(b0, fmaxf(b1, b2));
            float e0 = expf(b0 - m), e1 = expf(b1 - m), e2 = expf(b2 - m);
            float inv = 1.0f / (e0 + e1 + e2);
            float c0 = e0 * inv, c1 = e1 * inv, c2 = e2 * inv;
            const float* uh = uh_b + (size_t)i * 48;
#pragma unroll
            for (int d = 0; d < 16; d++) {
                sp[d]      = fmaf(c0, uh[d],      sp[d]);
                sp[16 + d] = fmaf(c1, uh[16 + d], sp[16 + d]);
                sp[32 + d] = fmaf(c2, uh[32 + d], sp[32 + d]);
            }
        }

        const int lane = tid & 63, wv = tid >> 6;
#pragma unroll
        for (int j = 0; j < 48; j++) {
            float x = sp[j];
            for (int off = 32; off; off >>= 1) x += __shfl_down(x, off, 64);
            if (lane == 0) red[wv][j] = x;
        }
        __syncthreads();
        if (tid < 48) {
            float x = 0.0f;
#pragma unroll
            for (int k = 0; k < 16; k++) x += red[k][tid];
            vsh[tid] = x;
        }
        __syncthreads();
        if (tid < 3) {
            float n2 = 0.0f;
            for (int d = 0; d < 16; d++) n2 = fmaf(vsh[tid * 16 + d], vsh[tid * 16 + d], n2);
            float n = sqrtf(n2);
            fac[tid] = (n2 / (1.0f + n2)) / (n + 1e-8f);
        }
        __syncthreads();
        if (tid < 48) vsh[tid] = vsh[tid] * fac[tid / 16];
        __syncthreads();

        if (it < 2) {
#pragma unroll
            for (int k = 0; k < 2; k++) {
                const int i = tid + k * 1024;
                const float* uh = uh_b + (size_t)i * 48;
                float a0 = 0.0f, a1 = 0.0f, a2 = 0.0f;
#pragma unroll
                for (int d = 0; d < 16; d++) {
                    a0 = fmaf(uh[d],      vsh[d],      a0);
                    a1 = fmaf(uh[16 + d], vsh[16 + d], a1);
                    a2 = fmaf(uh[32 + d], vsh[32 + d], a2);
                }
                blds[i * 3 + 0] += a0;
                blds[i * 3 + 1] += a1;
                blds[i * 3 + 2] += a2;
            }
            __syncthreads();
        }
    }

    if (tid < 3) {
        float n2 = 0.0f;
        for (int d = 0; d < 16; d++) n2 = fmaf(vsh[tid * 16 + d], vsh[tid * 16 + d], n2);
        out[b * 3 + tid] = sqrtf(n2);
    }
}

// ---------------------------------------------------------------------------
extern "C" void kernel_launch(void* const* d_in, const int* in_sizes, int n_in,
                              void* d_out, int out_size, void* d_ws, size_t ws_size,
                              hipStream_t stream)
{
    const float* x       = (const float*)d_in[0];
    const float* conv1_w = (const float*)d_in[1];
    const float* bn1_g   = (const float*)d_in[2];
    const float* bn1_b   = (const float*)d_in[3];
    const float* se1_w1  = (const float*)d_in[4];
    const float* se1_b1  = (const float*)d_in[5];
    const float* se1_w2  = (const float*)d_in[6];
    const float* se1_b2  = (const float*)d_in[7];
    const float* conv2_w = (const float*)d_in[8];
    const float* bn2_g   = (const float*)d_in[9];
    const float* bn2_b   = (const float*)d_in[10];
    const float* se2_w1  = (const float*)d_in[11];
    const float* se2_b1  = (const float*)d_in[12];
    const float* se2_w2  = (const float*)d_in[13];
    const float* se2_b2  = (const float*)d_in[14];
    const float* conv3_w = (const float*)d_in[15];
    const float* bn3_g   = (const float*)d_in[16];
    const float* bn3_b   = (const float*)d_in[17];
    const float* se3_w1  = (const float*)d_in[18];
    const float* se3_b1  = (const float*)d_in[19];
    const float* se3_w2  = (const float*)d_in[20];
    const float* se3_b2  = (const float*)d_in[21];
    const float* pc_w    = (const float*)d_in[22];
    const float* pc_b    = (const float*)d_in[23];
    const float* W_digit = (const float*)d_in[24];  // (1,2048,3,16,8)

    float* ws = (float*)d_ws;
    float* h1    = ws;                  // (64,16,128,128)
    float* h2    = ws + 16777216;       // (64,32,64,64)
    float* h3    = ws;                  // (64,64,32,32)  (overlays dead h1)
    float* u_raw = ws + 4194304;        // (64,64,16,16)
    float* u     = ws + 5242880;        // (64,2048,8)
    float* u_hat = ws + 6291456;        // (64,2048,48)
    float* sums  = ws + 25165824;       // [s1 1024][s2 2048][s3 4096]
    float* s1 = sums, *s2 = sums + 1024, *s3 = sums + 3072;

    hipMemsetAsync(sums, 0, 7168 * sizeof(float), stream);

    // conv1: 1->16, 128x128, s1, BN+ReLU, SE sums.  TW=128,ROWS_T=2,PPT=2 (TH=4)
    convt_k<1, 16, 16, 128, 128, 1, 128, 2, 2, 1, 256, true, true, 0>
        <<<dim3(32, 1, 64), 256, 0, stream>>>(
            x, conv1_w, bn1_g, bn1_b, h1, s1,
            nullptr, nullptr, nullptr, nullptr, nullptr, 0.0f);

    // conv2: 16->32, ->64x64, s2. SE1 MLP in-kernel. TW=64,ROWS_T=4,PPT=2 (TH=8)
    convt_k<16, 32, 16, 128, 64, 2, 64, 4, 2, 2, 256, true, true, 1>
        <<<dim3(8, 2, 64), 256, 0, stream>>>(
            h1, conv2_w, bn2_g, bn2_b, h2, s2,
            s1, se1_w1, se1_b1, se1_w2, se1_b2, 1.0f / 16384.0f);

    // conv3: 32->64, ->32x32, s2. SE2 MLP in-kernel. TW=32,ROWS_T=16,PPT=2 (TH=32), 512 thr
    convt_k<32, 64, 8, 64, 32, 2, 32, 16, 2, 2, 512, true, true, 2>
        <<<dim3(1, 8, 64), 512, 0, stream>>>(
            h2, conv3_w, bn3_g, bn3_b, h3, s3,
            s2, se2_w1, se2_b1, se2_w2, se2_b2, 1.0f / 4096.0f);

    // primary caps: 64->64, ->16x16, s2, +bias. SE3 MLP in-kernel. TW=16,ROWS_T=16,PPT=1
    convt_k<64, 64, 8, 32, 16, 2, 16, 16, 1, 4, 256, false, false, 4>
        <<<dim3(1, 8, 64), 256, 0, stream>>>(
            h3, pc_w, pc_b, nullptr, u_raw, nullptr,
            s3, se3_w1, se3_b1, se3_w2, se3_b2, 1.0f / 1024.0f);

    squash_k<<<512, 256, 0, stream>>>(u_raw, u);
    uhat_k<<<24576, 256, 0, stream>>>(u, W_digit, u_hat);
    routing_k<<<64, 1024, 0, stream>>>(u_hat, (float*)d_out);
}

// Round 4
// 398.079 us; speedup vs baseline: 1.5218x; 1.3025x over previous
//
#include <hip/hip_runtime.h>
#include <math.h>

#define BN_INV_F 0.9999950000374997f

// ---------------------------------------------------------------------------
// LDS-staged tiled direct 3x3 conv, pad=1.
//  - two-phase staging: global->regs (clustered loads), then regs->LDS
//  - next chunk's global loads issued before the compute barrier (latency
//    hidden under previous chunk's FMAs)
//  - SE scale of previous block computed in-kernel (HSE_IN>0), folded in at
//    LDS-write time
//  - epilogue: BN+ReLU (BN_RELU) or +bias; optional per-(b,cout) SE sums
// Thread layout: NTHREADS = TW * ROWS_T; thread owns PPT rows (rg + p*ROWS_T)
// at column wo, computes COB output channels. Tiles span the FULL output
// width (TW == WOUT); grid.x tiles rows only.
// grid = (HOUT/(ROWS_T*PPT), COUT/COB, B)
// ---------------------------------------------------------------------------
template <int CIN, int COUT, int COB, int HIN, int HOUT, int STRIDE,
          int TW, int ROWS_T, int PPT, int CB, int NTHREADS,
          bool BN_RELU, bool SE_SUM, int HSE_IN>
__global__ __launch_bounds__(NTHREADS) void convt_k(
    const float* __restrict__ in, const float* __restrict__ w,
    const float* __restrict__ gamma,     // BN gamma (BN_RELU) or bias
    const float* __restrict__ beta,      // BN beta  (BN_RELU) or unused
    float* __restrict__ out,
    float* __restrict__ se_sum,          // out: per (b,cout) sums (SE_SUM)
    const float* __restrict__ se_sums_in,// in: prev-block sums (HSE_IN>0)
    const float* __restrict__ se_w1, const float* __restrict__ se_b1,
    const float* __restrict__ se_w2, const float* __restrict__ se_b2,
    float inv_spatial)
{
    constexpr int WIN = HIN, WOUT = HOUT;
    constexpr int TH = ROWS_T * PPT;
    constexpr int IH_T = (TH - 1) * STRIDE + 3;
    constexpr int IW_T = (TW - 1) * STRIDE + 3;
    constexpr int NW = NTHREADS / 64;
    constexpr int STAGE_N = CB * IH_T * IW_T;
    constexpr int NLD = (STAGE_N + NTHREADS - 1) / NTHREADS;
    constexpr int NCHUNK = CIN / CB;
    static_assert(NTHREADS == TW * ROWS_T, "geometry");
    static_assert(TW == WOUT, "tile must span full output width");
    static_assert(CIN % CB == 0, "chunking");

    const int b = blockIdx.z;
    const int g = blockIdx.y;
    const int ty = blockIdx.x;
    const int tid = threadIdx.x;
    const int wo = tid % TW;
    const int rg = tid / TW;

    __shared__ float wl[CIN * 9 * COB];
    __shared__ float in_t[STAGE_N];
    __shared__ float scl[CIN];
    __shared__ float gl[COB], bl[COB];
    __shared__ float red[NW][COB];
    __shared__ float hid[HSE_IN > 0 ? HSE_IN : 1];

    const float* inb = in + (size_t)b * CIN * HIN * WIN;
    const int gr0 = ty * TH * STRIDE - 1;
    const int wos = wo * STRIDE;

    float sv[NLD];

    auto load_chunk = [&](int cb0, float* dst) {
#pragma unroll
        for (int k = 0; k < NLD; ++k) {
            int idx = tid + k * NTHREADS;
            float v = 0.0f;
            if (idx < STAGE_N) {
                int ci = idx / (IH_T * IW_T);
                int rem = idx % (IH_T * IW_T);
                int lr = rem / IW_T, lc = rem % IW_T;
                int gr = gr0 + lr, gc = lc - 1;
                if (gr >= 0 && gr < HIN && gc >= 0 && gc < WIN)
                    v = inb[(size_t)(cb0 + ci) * HIN * WIN + gr * WIN + gc];
            }
            dst[k] = v;
        }
    };
    load_chunk(0, sv);

    // stage weights: wl[(cin*9+k)*COB + col]
    for (int t = tid; t < CIN * 9 * COB; t += NTHREADS) {
        int col = t % COB;
        int rk = t / COB;
        int cin = rk / 9, k = rk % 9;
        wl[t] = w[((size_t)(g * COB + col) * CIN + cin) * 9 + k];
    }
    if (tid < COB) {
        int co = g * COB + tid;
        if (BN_RELU) {
            gl[tid] = gamma[co] * BN_INV_F;
            bl[tid] = beta[co];
        } else {
            gl[tid] = gamma[co];
        }
    }
    // input SE scale (previous block) computed in-kernel
    if (HSE_IN > 0) {
        if (tid < HSE_IN) {
            float a = se_b1[tid];
            for (int c = 0; c < CIN; ++c)
                a = fmaf(se_sums_in[b * CIN + c] * inv_spatial, se_w1[tid * CIN + c], a);
            hid[tid] = fmaxf(a, 0.0f);
        }
        __syncthreads();
        if (tid < CIN) {
            float a = se_b2[tid];
            for (int h = 0; h < HSE_IN; ++h)
                a = fmaf(hid[h], se_w2[tid * HSE_IN + h], a);
            scl[tid] = 1.0f / (1.0f + expf(-a));
        }
    } else {
        for (int t = tid; t < CIN; t += NTHREADS) scl[t] = 1.0f;
    }

    float acc[PPT][COB];
#pragma unroll
    for (int p = 0; p < PPT; ++p)
#pragma unroll
        for (int co = 0; co < COB; ++co) acc[p][co] = 0.0f;

    for (int c = 0; c < NCHUNK; ++c) {
        const int cb0 = c * CB;
        __syncthreads();  // in_t free (prev compute done); wl/scl visible
#pragma unroll
        for (int k = 0; k < NLD; ++k) {
            int idx = tid + k * NTHREADS;
            if (idx < STAGE_N) {
                int ci = idx / (IH_T * IW_T);
                in_t[idx] = sv[k] * scl[cb0 + ci];
            }
        }
        // issue next chunk's loads; they fly under this chunk's compute
        if (c + 1 < NCHUNK) load_chunk(cb0 + CB, sv);
        __syncthreads();

        for (int ci = 0; ci < CB; ++ci) {
#pragma unroll
            for (int kh = 0; kh < 3; ++kh) {
#pragma unroll
                for (int kw = 0; kw < 3; ++kw) {
                    const float* wrow = &wl[((cb0 + ci) * 9 + kh * 3 + kw) * COB];
                    float wv[COB];
#pragma unroll
                    for (int co = 0; co < COB; ++co) wv[co] = wrow[co];
#pragma unroll
                    for (int p = 0; p < PPT; ++p) {
                        float v = in_t[(ci * IH_T + (rg + p * ROWS_T) * STRIDE + kh) * IW_T + wos + kw];
#pragma unroll
                        for (int co = 0; co < COB; ++co)
                            acc[p][co] = fmaf(wv[co], v, acc[p][co]);
                    }
                }
            }
        }
    }

    // epilogue
    float tsum[COB];
#pragma unroll
    for (int co = 0; co < COB; ++co) tsum[co] = 0.0f;
    float* outb = out + ((size_t)b * COUT + g * COB) * HOUT * WOUT;
#pragma unroll
    for (int p = 0; p < PPT; ++p) {
        const int ho = ty * TH + rg + p * ROWS_T;
#pragma unroll
        for (int co = 0; co < COB; ++co) {
            float v;
            if (BN_RELU)
                v = fmaxf(fmaf(acc[p][co], gl[co], bl[co]), 0.0f);
            else
                v = acc[p][co] + gl[co];
            outb[(size_t)co * HOUT * WOUT + ho * WOUT + wo] = v;
            tsum[co] += v;
        }
    }

    if (SE_SUM) {
        const int lane = tid & 63, wv2 = tid >> 6;
#pragma unroll
        for (int co = 0; co < COB; ++co) {
            float v = tsum[co];
            for (int off = 32; off; off >>= 1) v += __shfl_down(v, off, 64);
            if (lane == 0) red[wv2][co] = v;
        }
        __syncthreads();
        if (tid < COB) {
            float v = 0.0f;
#pragma unroll
            for (int k = 0; k < NW; ++k) v += red[k][tid];
            atomicAdd(&se_sum[b * COUT + g * COB + tid], v);
        }
    }
}

// ---------------------------------------------------------------------------
// Capsule squash. u_raw: (B,64,16,16) NCHW. cap i = (c>>3)*256 + h*16 + w,
// component j = c&7. u out: (B,2048,8).
// ---------------------------------------------------------------------------
__global__ __launch_bounds__(256) void squash_k(const float* __restrict__ u_raw,
                                                float* __restrict__ u)
{
    const int idx = blockIdx.x * 256 + threadIdx.x;  // b*2048 + i
    const int b = idx >> 11, i = idx & 2047;
    const int chi = i >> 8, spx = i & 255;
    const float* p = u_raw + ((size_t)(b * 64 + chi * 8)) * 256 + spx;
    float s[8];
    float n2 = 0.0f;
#pragma unroll
    for (int j = 0; j < 8; j++) {
        s[j] = p[(size_t)j * 256];
        n2 = fmaf(s[j], s[j], n2);
    }
    const float n = sqrtf(n2);
    const float f = (n2 / (1.0f + n2)) / (n + 1e-8f);
    float* q = u + (size_t)idx * 8;
#pragma unroll
    for (int j = 0; j < 8; j++) q[j] = s[j] * f;
}

// ---------------------------------------------------------------------------
// u_hat[b,i,c,d] = sum_e W[i,c,d,e] * u[b,i,e]
// ---------------------------------------------------------------------------
__global__ __launch_bounds__(256) void uhat_k(const float* __restrict__ u,
                                              const float* __restrict__ W,
                                              float* __restrict__ u_hat)
{
    const int idx = blockIdx.x * 256 + threadIdx.x;  // (b*2048+i)*48 + cd
    const int cd = idx % 48;
    const int bi = idx / 48;
    const int i = bi & 2047;
    const float* uu = u + (size_t)bi * 8;
    const float* wp = W + (size_t)i * 384 + cd * 8;
    float a = 0.0f;
#pragma unroll
    for (int e = 0; e < 8; e++) a = fmaf(wp[e], uu[e], a);
    u_hat[idx] = a;
}

// ---------------------------------------------------------------------------
// Dynamic routing, 3 iters, one 1024-thread block per batch element.
// ---------------------------------------------------------------------------
__global__ __launch_bounds__(1024) void routing_k(const float* __restrict__ u_hat,
                                                  float* __restrict__ out)
{
    const int b = blockIdx.x;
    const int tid = threadIdx.x;
    __shared__ float blds[2048 * 3];
    __shared__ float red[16][48];
    __shared__ float vsh[48];
    __shared__ float fac[3];

    for (int t = tid; t < 2048 * 3; t += 1024) blds[t] = 0.0f;
    __syncthreads();

    const float* uh_b = u_hat + (size_t)b * 2048 * 48;

    for (int it = 0; it < 3; ++it) {
        float sp[48];
#pragma unroll
        for (int j = 0; j < 48; j++) sp[j] = 0.0f;

#pragma unroll
        for (int k = 0; k < 2; k++) {
            const int i = tid + k * 1024;
            float b0 = blds[i * 3 + 0], b1 = blds[i * 3 + 1], b2 = blds[i * 3 + 2];
            float m = fmaxf(b0, fmaxf(b1, b2));
            float e0 = expf(b0 - m), e1 = expf(b1 - m), e2 = expf(b2 - m);
            float inv = 1.0f / (e0 + e1 + e2);
            float c0 = e0 * inv, c1 = e1 * inv, c2 = e2 * inv;
            const float* uh = uh_b + (size_t)i * 48;
#pragma unroll
            for (int d = 0; d < 16; d++) {
                sp[d]      = fmaf(c0, uh[d],      sp[d]);
                sp[16 + d] = fmaf(c1, uh[16 + d], sp[16 + d]);
                sp[32 + d] = fmaf(c2, uh[32 + d], sp[32 + d]);
            }
        }

        const int lane = tid & 63, wv = tid >> 6;
#pragma unroll
        for (int j = 0; j < 48; j++) {
            float x = sp[j];
            for (int off = 32; off; off >>= 1) x += __shfl_down(x, off, 64);
            if (lane == 0) red[wv][j] = x;
        }
        __syncthreads();
        if (tid < 48) {
            float x = 0.0f;
#pragma unroll
            for (int k = 0; k < 16; k++) x += red[k][tid];
            vsh[tid] = x;
        }
        __syncthreads();
        if (tid < 3) {
            float n2 = 0.0f;
            for (int d = 0; d < 16; d++) n2 = fmaf(vsh[tid * 16 + d], vsh[tid * 16 + d], n2);
            float n = sqrtf(n2);
            fac[tid] = (n2 / (1.0f + n2)) / (n + 1e-8f);
        }
        __syncthreads();
        if (tid < 48) vsh[tid] = vsh[tid] * fac[tid / 16];
        __syncthreads();

        if (it < 2) {
#pragma unroll
            for (int k = 0; k < 2; k++) {
                const int i = tid + k * 1024;
                const float* uh = uh_b + (size_t)i * 48;
                float a0 = 0.0f, a1 = 0.0f, a2 = 0.0f;
#pragma unroll
                for (int d = 0; d < 16; d++) {
                    a0 = fmaf(uh[d],      vsh[d],      a0);
                    a1 = fmaf(uh[16 + d], vsh[16 + d], a1);
                    a2 = fmaf(uh[32 + d], vsh[32 + d], a2);
                }
                blds[i * 3 + 0] += a0;
                blds[i * 3 + 1] += a1;
                blds[i * 3 + 2] += a2;
            }
            __syncthreads();
        }
    }

    if (tid < 3) {
        float n2 = 0.0f;
        for (int d = 0; d < 16; d++) n2 = fmaf(vsh[tid * 16 + d], vsh[tid * 16 + d], n2);
        out[b * 3 + tid] = sqrtf(n2);
    }
}

// ---------------------------------------------------------------------------
extern "C" void kernel_launch(void* const* d_in, const int* in_sizes, int n_in,
                              void* d_out, int out_size, void* d_ws, size_t ws_size,
                              hipStream_t stream)
{
    const float* x       = (const float*)d_in[0];
    const float* conv1_w = (const float*)d_in[1];
    const float* bn1_g   = (const float*)d_in[2];
    const float* bn1_b   = (const float*)d_in[3];
    const float* se1_w1  = (const float*)d_in[4];
    const float* se1_b1  = (const float*)d_in[5];
    const float* se1_w2  = (const float*)d_in[6];
    const float* se1_b2  = (const float*)d_in[7];
    const float* conv2_w = (const float*)d_in[8];
    const float* bn2_g   = (const float*)d_in[9];
    const float* bn2_b   = (const float*)d_in[10];
    const float* se2_w1  = (const float*)d_in[11];
    const float* se2_b1  = (const float*)d_in[12];
    const float* se2_w2  = (const float*)d_in[13];
    const float* se2_b2  = (const float*)d_in[14];
    const float* conv3_w = (const float*)d_in[15];
    const float* bn3_g   = (const float*)d_in[16];
    const float* bn3_b   = (const float*)d_in[17];
    const float* se3_w1  = (const float*)d_in[18];
    const float* se3_b1  = (const float*)d_in[19];
    const float* se3_w2  = (const float*)d_in[20];
    const float* se3_b2  = (const float*)d_in[21];
    const float* pc_w    = (const float*)d_in[22];
    const float* pc_b    = (const float*)d_in[23];
    const float* W_digit = (const float*)d_in[24];  // (1,2048,3,16,8)

    float* ws = (float*)d_ws;
    float* h1    = ws;                  // (64,16,128,128)
    float* h2    = ws + 16777216;       // (64,32,64,64)
    float* h3    = ws;                  // (64,64,32,32)  (overlays dead h1)
    float* u_raw = ws + 4194304;        // (64,64,16,16)
    float* u     = ws + 5242880;        // (64,2048,8)
    float* u_hat = ws + 6291456;        // (64,2048,48)
    float* sums  = ws + 25165824;       // [s1 1024][s2 2048][s3 4096]
    float* s1 = sums, *s2 = sums + 1024, *s3 = sums + 3072;

    hipMemsetAsync(sums, 0, 7168 * sizeof(float), stream);

    // conv1: 1->16, 128x128, s1, BN+ReLU, SE sums.
    // TW=128(=WOUT), ROWS_T=2, PPT=4 (TH=8), CB=1, grid (16,1,64)
    convt_k<1, 16, 16, 128, 128, 1, 128, 2, 4, 1, 256, true, true, 0>
        <<<dim3(16, 1, 64), 256, 0, stream>>>(
            x, conv1_w, bn1_g, bn1_b, h1, s1,
            nullptr, nullptr, nullptr, nullptr, nullptr, 0.0f);

    // conv2: 16->32, ->64x64, s2. COB=32 (g=1, no restage). SE1 MLP in-kernel.
    // TW=64, ROWS_T=4, PPT=2 (TH=8), CB=4, grid (8,1,64)
    convt_k<16, 32, 32, 128, 64, 2, 64, 4, 2, 4, 256, true, true, 1>
        <<<dim3(8, 1, 64), 256, 0, stream>>>(
            h1, conv2_w, bn2_g, bn2_b, h2, s2,
            s1, se1_w1, se1_b1, se1_w2, se1_b2, 1.0f / 16384.0f);

    // conv3: 32->64, ->32x32, s2. COB=32 (g=2). SE2 MLP in-kernel.
    // TW=32, ROWS_T=8, PPT=1 (TH=8), CB=4, grid (4,2,64)
    convt_k<32, 64, 32, 64, 32, 2, 32, 8, 1, 4, 256, true, true, 2>
        <<<dim3(4, 2, 64), 256, 0, stream>>>(
            h2, conv3_w, bn3_g, bn3_b, h3, s3,
            s2, se2_w1, se2_b1, se2_w2, se2_b2, 1.0f / 4096.0f);

    // primary caps: 64->64, ->16x16, s2, +bias. COB=16 (g=4). SE3 MLP in-kernel.
    // TW=16, ROWS_T=16, PPT=1 (TH=16), CB=8, grid (1,4,64)
    convt_k<64, 64, 16, 32, 16, 2, 16, 16, 1, 8, 256, false, false, 4>
        <<<dim3(1, 4, 64), 256, 0, stream>>>(
            h3, pc_w, pc_b, nullptr, u_raw, nullptr,
            s3, se3_w1, se3_b1, se3_w2, se3_b2, 1.0f / 1024.0f);

    squash_k<<<512, 256, 0, stream>>>(u_raw, u);
    uhat_k<<<24576, 256, 0, stream>>>(u, W_digit, u_hat);
    routing_k<<<64, 1024, 0, stream>>>(u_hat, (float*)d_out);
}

// Round 5
// 333.874 us; speedup vs baseline: 1.8145x; 1.1923x over previous
//
#include <hip/hip_runtime.h>
#include <math.h>

#define BN_INV_F 0.9999950000374997f

__device__ __forceinline__ void gload_lds4(const float* g, float* l) {
    __builtin_amdgcn_global_load_lds(
        (const __attribute__((address_space(1))) void*)g,
        (__attribute__((address_space(3))) void*)l, 4, 0, 0);
}

// ---------------------------------------------------------------------------
// LDS-staged tiled direct 3x3 conv, pad=1, full-width tiles (TW == WOUT).
//  - global_load_lds staging, interior-only rows [ci][IH_T][WIN], dbuf chunks
//  - SE scale of previous block computed in-kernel, folded into WEIGHTS
//  - optional CIN split (KSPLIT=2): grid.y = NG*KSPLIT, partials to out/out2
//  - epilogue: BN+ReLU (BN_RELU) or +bias (bias only for kk==0)
// grid = (HOUT/(ROWS_T*PPT), (COUT/COB)*KSPLIT, B), block = TW*ROWS_T
// ---------------------------------------------------------------------------
template <int CIN, int CINB, int COB, int HIN, int HOUT, int STRIDE,
          int TW, int ROWS_T, int PPT, int CB, int NTHREADS,
          bool BN_RELU, bool SE_SUM, int HSE_IN, int KSPLIT>
__global__ __launch_bounds__(NTHREADS) void convt_k(
    const float* __restrict__ in, const float* __restrict__ w,
    const float* __restrict__ gamma,     // BN gamma (BN_RELU) or bias
    const float* __restrict__ beta,      // BN beta  (BN_RELU) or unused
    float* __restrict__ out,
    float* __restrict__ out2,            // partials for kk==1 (KSPLIT==2)
    float* __restrict__ se_sum,          // out: per (b,cout) sums (SE_SUM)
    const float* __restrict__ se_sums_in,// in: prev-block sums (HSE_IN>0)
    const float* __restrict__ se_w1, const float* __restrict__ se_b1,
    const float* __restrict__ se_w2, const float* __restrict__ se_b2,
    float inv_spatial)
{
    constexpr int WIN = HIN, WOUT = HOUT;
    constexpr int TH = ROWS_T * PPT;
    constexpr int IH_T = (TH - 1) * STRIDE + 3;
    constexpr int NW = NTHREADS / 64;
    constexpr int NCHUNK = CINB / CB;
    constexpr int NG = 64 / COB >= 1 ? ( (BN_RELU||true) ? ( ( ( ( (0) ) ) ) , ( ( ( ( ( ( ( ( ( ( (0) ) ) ) ) ) ) ) ) ) ) , ( ( ( ( (COB) ) ) ) ) ? 0 : 0 ) : 0 ) : 0; // (unused placeholder)
    constexpr int SEGS = (WIN >= 64) ? (WIN / 64) : 1;
    constexpr int PAIRS = (IH_T + 1) / 2;
    static_assert(NTHREADS == TW * ROWS_T, "geometry");
    static_assert(TW == WOUT, "tile must span full output width");
    static_assert(CINB % CB == 0, "chunking");
    static_assert(WIN % 64 == 0 || WIN == 32, "stage width");

    const int b = blockIdx.z;
    const int gy = blockIdx.y;
    const int ty = blockIdx.x;
    const int tid = threadIdx.x;
    const int wo = tid % TW;
    const int rg = tid / TW;

    __shared__ float wl[CINB * 9 * COB];
    __shared__ float in_t[2][CB * IH_T * WIN];
    __shared__ float scl[CIN];
    __shared__ float gl[COB], bl[COB];
    __shared__ float red[NW][COB];
    __shared__ float hid[HSE_IN > 0 ? HSE_IN : 1];

    // decompose grid.y into cout group g and cin-split kk
    constexpr int NGRP = (KSPLIT == 2) ? 2 : 1;  // splits
    const int ng = gridDim.y / NGRP;             // cout groups
    const int g = gy % ng;
    const int kk = gy / ng;
    const int cin0 = kk * CINB;

    const float* inb = in + (size_t)b * CIN * HIN * WIN;
    const int gr0 = ty * TH * STRIDE - 1;
    const int wos = wo * STRIDE;
    const int wvid = tid >> 6, lane = tid & 63;

    auto stage = [&](int c, int buf) {
        const int cb0 = cin0 + c * CB;
        float* bb = &in_t[buf][0];
        if (WIN >= 64) {
            for (int r = wvid; r < CB * IH_T; r += NW) {
                int ci = r / IH_T, lr = r - ci * IH_T;
                int gr = gr0 + lr;
                float* ldst = bb + (ci * IH_T + lr) * WIN;
                if (gr >= 0 && gr < HIN) {
                    const float* gsrc = inb + (size_t)(cb0 + ci) * HIN * WIN + (size_t)gr * WIN;
#pragma unroll
                    for (int s = 0; s < SEGS; ++s)
                        gload_lds4(gsrc + s * 64 + lane, ldst + s * 64);
                } else {
#pragma unroll
                    for (int s = 0; s < SEGS; ++s) ldst[s * 64 + lane] = 0.0f;
                }
            }
        } else {  // WIN == 32: row pairs per wave-load
            for (int pz = wvid; pz < CB * PAIRS; pz += NW) {
                int ci = pz / PAIRS, q = pz - ci * PAIRS;
                int lr0 = q * 2;
                int nr = (lr0 + 1 < IH_T) ? 2 : 1;
                int grr = gr0 + lr0;
                float* ldst = bb + (ci * IH_T + lr0) * WIN;
                if (nr == 2 && grr >= 0 && grr + 1 < HIN) {
                    const float* gsrc = inb + (size_t)(cb0 + ci) * HIN * WIN + (size_t)grr * WIN + lane;
                    gload_lds4(gsrc, ldst);
                } else {
                    for (int e = lane; e < nr * WIN; e += 64) {
                        int rr = e / WIN, cc = e - rr * WIN;
                        int gr = grr + rr;
                        ldst[e] = (gr >= 0 && gr < HIN)
                            ? inb[(size_t)(cb0 + ci) * HIN * WIN + (size_t)gr * WIN + cc] : 0.0f;
                    }
                }
            }
        }
    };

    stage(0, 0);  // chunk-0 DMA flies under SE-MLP + weight staging

    // ---- SE scale of previous block (per b, per cin) ----
    if (HSE_IN > 0) {
        if (tid < HSE_IN) {
            float a = se_b1[tid];
            for (int c = 0; c < CIN; ++c)
                a = fmaf(se_sums_in[b * CIN + c] * inv_spatial, se_w1[tid * CIN + c], a);
            hid[tid] = fmaxf(a, 0.0f);
        }
        __syncthreads();
        if (tid < CIN) {
            float a = se_b2[tid];
            for (int h = 0; h < HSE_IN; ++h)
                a = fmaf(hid[h], se_w2[tid * HSE_IN + h], a);
            scl[tid] = 1.0f / (1.0f + expf(-a));
        }
    } else {
        for (int t = tid; t < CIN; t += NTHREADS) scl[t] = 1.0f;
    }
    __syncthreads();  // scl visible

    // ---- weights (SE scale folded in) ----
    for (int t = tid; t < CINB * 9 * COB; t += NTHREADS) {
        int col = t % COB;
        int rk = t / COB;
        int cin = rk / 9, k = rk % 9;
        wl[t] = w[((size_t)(g * COB + col) * CIN + cin0 + cin) * 9 + k] * scl[cin0 + cin];
    }
    if (tid < COB) {
        int co = g * COB + tid;
        if (BN_RELU) {
            gl[tid] = gamma[co] * BN_INV_F;
            bl[tid] = beta[co];
        } else {
            gl[tid] = (KSPLIT == 2 && kk == 1) ? 0.0f : gamma[co];
        }
    }

    float acc[PPT][COB];
#pragma unroll
    for (int p = 0; p < PPT; ++p)
#pragma unroll
        for (int co = 0; co < COB; ++co) acc[p][co] = 0.0f;

    int cur = 0;
    for (int c = 0; c < NCHUNK; ++c) {
        asm volatile("s_waitcnt vmcnt(0)" ::: "memory");
        __syncthreads();  // buf[cur] staged; wl/scl visible (first iter)
        if (c + 1 < NCHUNK) stage(c + 1, cur ^ 1);

        const float* bb = &in_t[cur][0];
        for (int ci = 0; ci < CB; ++ci) {
            const int cw = c * CB + ci;
#pragma unroll
            for (int kh = 0; kh < 3; ++kh) {
#pragma unroll
                for (int kw = 0; kw < 3; ++kw) {
                    const float* wrow = &wl[(cw * 9 + kh * 3 + kw) * COB];
                    float wv[COB];
#pragma unroll
                    for (int co = 0; co < COB; ++co) wv[co] = wrow[co];
#pragma unroll
                    for (int p = 0; p < PPT; ++p) {
                        const float* row = bb + (ci * IH_T + (rg + p * ROWS_T) * STRIDE + kh) * WIN;
                        int wi = wos + kw - 1;
                        float v;
                        if (kw == 0) {
                            v = row[wi < 0 ? 0 : wi];
                            if (wi < 0) v = 0.0f;
                        } else if (STRIDE == 1 && kw == 2) {
                            v = row[wi >= WIN ? WIN - 1 : wi];
                            if (wi >= WIN) v = 0.0f;
                        } else {
                            v = row[wi];
                        }
#pragma unroll
                        for (int co = 0; co < COB; ++co)
                            acc[p][co] = fmaf(wv[co], v, acc[p][co]);
                    }
                }
            }
        }
        cur ^= 1;
    }

    // epilogue
    float tsum[COB];
#pragma unroll
    for (int co = 0; co < COB; ++co) tsum[co] = 0.0f;
    float* ob = ((KSPLIT == 2 && kk == 1) ? out2 : out)
                + ((size_t)b * 64 + (size_t)g * COB) * HOUT * WOUT;  // COUT==64 or 16/32: use below
    // note: COUT = ng*COB; recompute properly:
    ob = ((KSPLIT == 2 && kk == 1) ? out2 : out)
         + ((size_t)b * (size_t)(ng * COB) + (size_t)g * COB) * HOUT * WOUT;
#pragma unroll
    for (int p = 0; p < PPT; ++p) {
        const int ho = ty * TH + rg + p * ROWS_T;
#pragma unroll
        for (int co = 0; co < COB; ++co) {
            float v;
            if (BN_RELU)
                v = fmaxf(fmaf(acc[p][co], gl[co], bl[co]), 0.0f);
            else
                v = acc[p][co] + gl[co];
            ob[(size_t)co * HOUT * WOUT + ho * WOUT + wo] = v;
            tsum[co] += v;
        }
    }

    if (SE_SUM) {
#pragma unroll
        for (int co = 0; co < COB; ++co) {
            float v = tsum[co];
            for (int off = 32; off; off >>= 1) v += __shfl_down(v, off, 64);
            if (lane == 0) red[wvid][co] = v;
        }
        __syncthreads();
        if (tid < COB) {
            float v = 0.0f;
#pragma unroll
            for (int k = 0; k < NW; ++k) v += red[k][tid];
            atomicAdd(&se_sum[b * (ng * COB) + g * COB + tid], v);
        }
    }
}

// ---------------------------------------------------------------------------
// Capsule squash over sum of two partial buffers.
// ---------------------------------------------------------------------------
__global__ __launch_bounds__(256) void squash2_k(const float* __restrict__ ua,
                                                 const float* __restrict__ ub,
                                                 float* __restrict__ u)
{
    const int idx = blockIdx.x * 256 + threadIdx.x;  // b*2048 + i
    const int b = idx >> 11, i = idx & 2047;
    const int chi = i >> 8, spx = i & 255;
    const size_t off = ((size_t)(b * 64 + chi * 8)) * 256 + spx;
    float s[8];
    float n2 = 0.0f;
#pragma unroll
    for (int j = 0; j < 8; j++) {
        s[j] = ua[off + (size_t)j * 256] + ub[off + (size_t)j * 256];
        n2 = fmaf(s[j], s[j], n2);
    }
    const float n = sqrtf(n2);
    const float f = (n2 / (1.0f + n2)) / (n + 1e-8f);
    float* q = u + (size_t)idx * 8;
#pragma unroll
    for (int j = 0; j < 8; j++) q[j] = s[j] * f;
}

// ---------------------------------------------------------------------------
// u_hat[b,i,c,d] = sum_e W[i,c,d,e] * u[b,i,e]
// ---------------------------------------------------------------------------
__global__ __launch_bounds__(256) void uhat_k(const float* __restrict__ u,
                                              const float* __restrict__ W,
                                              float* __restrict__ u_hat)
{
    const int idx = blockIdx.x * 256 + threadIdx.x;  // (b*2048+i)*48 + cd
    const int cd = idx % 48;
    const int bi = idx / 48;
    const int i = bi & 2047;
    const float* uu = u + (size_t)bi * 8;
    const float* wp = W + (size_t)i * 384 + cd * 8;
    float a = 0.0f;
#pragma unroll
    for (int e = 0; e < 8; e++) a = fmaf(wp[e], uu[e], a);
    u_hat[idx] = a;
}

// ---------------------------------------------------------------------------
// Dynamic routing, 3 merged sweeps (b-update fused into softmax pass).
// One 1024-thread block per batch element; b_ij in registers (2 caps/thread).
// ---------------------------------------------------------------------------
__global__ __launch_bounds__(1024) void routing_k(const float* __restrict__ u_hat,
                                                  float* __restrict__ out)
{
    const int b = blockIdx.x;
    const int tid = threadIdx.x;
    __shared__ float red[16][48];
    __shared__ float vsh[48];
    __shared__ float fac[3];

    float b0r[2] = {0.0f, 0.0f}, b1r[2] = {0.0f, 0.0f}, b2r[2] = {0.0f, 0.0f};
    const float* ub = u_hat + (size_t)b * 2048 * 48;

    for (int it = 0; it < 3; ++it) {
        float sp[48];
#pragma unroll
        for (int j = 0; j < 48; ++j) sp[j] = 0.0f;

#pragma unroll
        for (int k = 0; k < 2; ++k) {
            const int i = tid + k * 1024;
            const float4* qp = (const float4*)(ub + (size_t)i * 48);
            float uhv[48];
#pragma unroll
            for (int q = 0; q < 12; ++q) {
                float4 t = qp[q];
                uhv[q * 4 + 0] = t.x; uhv[q * 4 + 1] = t.y;
                uhv[q * 4 + 2] = t.z; uhv[q * 4 + 3] = t.w;
            }
            float c0, c1, c2;
            if (it == 0) {
                c0 = c1 = c2 = (1.0f / 3.0f);
            } else {
                float a0 = 0.0f, a1 = 0.0f, a2 = 0.0f;
#pragma unroll
                for (int d = 0; d < 16; ++d) {
                    a0 = fmaf(uhv[d],      vsh[d],      a0);
                    a1 = fmaf(uhv[16 + d], vsh[16 + d], a1);
                    a2 = fmaf(uhv[32 + d], vsh[32 + d], a2);
                }
                b0r[k] += a0; b1r[k] += a1; b2r[k] += a2;
                float m = fmaxf(b0r[k], fmaxf(b1r[k], b2r[k]));
                float e0 = expf(b0r[k] - m), e1 = expf(b1r[k] - m), e2 = expf(b2r[k] - m);
                float inv = 1.0f / (e0 + e1 + e2);
                c0 = e0 * inv; c1 = e1 * inv; c2 = e2 * inv;
            }
#pragma unroll
            for (int d = 0; d < 16; ++d) {
                sp[d]      = fmaf(c0, uhv[d],      sp[d]);
                sp[16 + d] = fmaf(c1, uhv[16 + d], sp[16 + d]);
                sp[32 + d] = fmaf(c2, uhv[32 + d], sp[32 + d]);
            }
        }

        const int lane = tid & 63, wv = tid >> 6;
#pragma unroll
        for (int j = 0; j < 48; ++j) {
            float x = sp[j];
            for (int off = 32; off; off >>= 1) x += __shfl_down(x, off, 64);
            if (lane == 0) red[wv][j] = x;
        }
        __syncthreads();
        if (tid < 48) {
            float x = 0.0f;
#pragma unroll
            for (int kk = 0; kk < 16; ++kk) x += red[kk][tid];
            vsh[tid] = x;
        }
        __syncthreads();
        if (tid < 3) {
            float n2 = 0.0f;
            for (int d = 0; d < 16; d++) n2 = fmaf(vsh[tid * 16 + d], vsh[tid * 16 + d], n2);
            float n = sqrtf(n2);
            fac[tid] = (n2 / (1.0f + n2)) / (n + 1e-8f);
        }
        __syncthreads();
        if (tid < 48) vsh[tid] = vsh[tid] * fac[tid / 16];
        __syncthreads();
    }

    if (tid < 3) {
        float n2 = 0.0f;
        for (int d = 0; d < 16; d++) n2 = fmaf(vsh[tid * 16 + d], vsh[tid * 16 + d], n2);
        out[b * 3 + tid] = sqrtf(n2);
    }
}

// ---------------------------------------------------------------------------
extern "C" void kernel_launch(void* const* d_in, const int* in_sizes, int n_in,
                              void* d_out, int out_size, void* d_ws, size_t ws_size,
                              hipStream_t stream)
{
    const float* x       = (const float*)d_in[0];
    const float* conv1_w = (const float*)d_in[1];
    const float* bn1_g   = (const float*)d_in[2];
    const float* bn1_b   = (const float*)d_in[3];
    const float* se1_w1  = (const float*)d_in[4];
    const float* se1_b1  = (const float*)d_in[5];
    const float* se1_w2  = (const float*)d_in[6];
    const float* se1_b2  = (const float*)d_in[7];
    const float* conv2_w = (const float*)d_in[8];
    const float* bn2_g   = (const float*)d_in[9];
    const float* bn2_b   = (const float*)d_in[10];
    const float* se2_w1  = (const float*)d_in[11];
    const float* se2_b1  = (const float*)d_in[12];
    const float* se2_w2  = (const float*)d_in[13];
    const float* se2_b2  = (const float*)d_in[14];
    const float* conv3_w = (const float*)d_in[15];
    const float* bn3_g   = (const float*)d_in[16];
    const float* bn3_b   = (const float*)d_in[17];
    const float* se3_w1  = (const float*)d_in[18];
    const float* se3_b1  = (const float*)d_in[19];
    const float* se3_w2  = (const float*)d_in[20];
    const float* se3_b2  = (const float*)d_in[21];
    const float* pc_w    = (const float*)d_in[22];
    const float* pc_b    = (const float*)d_in[23];
    const float* W_digit = (const float*)d_in[24];  // (1,2048,3,16,8)

    float* ws = (float*)d_ws;
    float* h1     = ws;                  // (64,16,128,128)
    float* h2     = ws + 16777216;       // (64,32,64,64)
    float* h3     = ws;                  // (64,64,32,32)  (overlays dead h1)
    float* u_rawA = ws + 4194304;        // (64,64,16,16)
    float* u      = ws + 5242880;        // (64,2048,8)
    float* u_hat  = ws + 6291456;        // (64,2048,48)
    float* u_rawB = ws + 12582912;       // (64,64,16,16) second partial
    float* sums   = ws + 25165824;       // [s1 1024][s2 2048][s3 4096]
    float* s1 = sums, *s2 = sums + 1024, *s3 = sums + 3072;

    hipMemsetAsync(sums, 0, 7168 * sizeof(float), stream);

    // conv1: 1->16, 128x128, s1. TW=128, ROWS_T=2, PPT=2 (TH=4), CB=1.
    convt_k<1, 1, 16, 128, 128, 1, 128, 2, 2, 1, 256, true, true, 0, 1>
        <<<dim3(32, 1, 64), 256, 0, stream>>>(
            x, conv1_w, bn1_g, bn1_b, h1, nullptr, s1,
            nullptr, nullptr, nullptr, nullptr, nullptr, 0.0f);

    // conv2: 16->32, ->64x64, s2. COB=32 (g=1). TW=64, ROWS_T=4, PPT=1 (TH=4), CB=2.
    convt_k<16, 16, 32, 128, 64, 2, 64, 4, 1, 2, 256, true, true, 1, 1>
        <<<dim3(16, 1, 64), 256, 0, stream>>>(
            h1, conv2_w, bn2_g, bn2_b, h2, nullptr, s2,
            s1, se1_w1, se1_b1, se1_w2, se1_b2, 1.0f / 16384.0f);

    // conv3: 32->64, ->32x32, s2. COB=16 (g=4). TW=32, ROWS_T=8, PPT=2 (TH=16), CB=2.
    convt_k<32, 32, 16, 64, 32, 2, 32, 8, 2, 2, 256, true, true, 2, 1>
        <<<dim3(2, 4, 64), 256, 0, stream>>>(
            h2, conv3_w, bn3_g, bn3_b, h3, nullptr, s3,
            s2, se2_w1, se2_b1, se2_w2, se2_b2, 1.0f / 4096.0f);

    // primary caps: 64->64, ->16x16, s2, +bias. COB=16 (g=4), CIN split x2.
    // TW=16, ROWS_T=16, PPT=1 (TH=16), CB=2. grid.y = 4*2.
    convt_k<64, 32, 16, 32, 16, 2, 16, 16, 1, 2, 256, false, false, 4, 2>
        <<<dim3(1, 8, 64), 256, 0, stream>>>(
            h3, pc_w, pc_b, nullptr, u_rawA, u_rawB, nullptr,
            s3, se3_w1, se3_b1, se3_w2, se3_b2, 1.0f / 1024.0f);

    squash2_k<<<512, 256, 0, stream>>>(u_rawA, u_rawB, u);
    uhat_k<<<24576, 256, 0, stream>>>(u, W_digit, u_hat);
    routing_k<<<64, 1024, 0, stream>>>(u_hat, (float*)d_out);
}

// Round 6
// 279.875 us; speedup vs baseline: 2.1645x; 1.1929x over previous
//
#include <hip/hip_runtime.h>
#include <math.h>

#define BN_INV_F 0.9999950000374997f

__device__ __forceinline__ void gload_lds4(const float* g, float* l) {
    __builtin_amdgcn_global_load_lds(
        (const __attribute__((address_space(1))) void*)g,
        (__attribute__((address_space(3))) void*)l, 4, 0, 0);
}

// ---------------------------------------------------------------------------
// LDS-staged tiled direct 3x3 conv, pad=1, full-width tiles (TW == WOUT).
//  - global_load_lds staging, interior-only rows [ci][IH_T][WIN], dbuf chunks
//  - SE scale of previous block computed in-kernel, folded into WEIGHTS
//  - optional CIN split (KSPLIT=2): grid.y = NG*KSPLIT, partials to out/out2
//  - weights read from LDS as float4 (ds_read_b128, broadcast)
// grid = (HOUT/(ROWS_T*PPT), (COUT/COB)*KSPLIT, B), block = TW*ROWS_T
// ---------------------------------------------------------------------------
template <int CIN, int CINB, int COB, int HIN, int HOUT, int STRIDE,
          int TW, int ROWS_T, int PPT, int CB, int NTHREADS,
          bool BN_RELU, bool SE_SUM, int HSE_IN, int KSPLIT>
__global__ __launch_bounds__(NTHREADS) void convt_k(
    const float* __restrict__ in, const float* __restrict__ w,
    const float* __restrict__ gamma,     // BN gamma (BN_RELU) or bias
    const float* __restrict__ beta,      // BN beta  (BN_RELU) or unused
    float* __restrict__ out,
    float* __restrict__ out2,            // partials for kk==1 (KSPLIT==2)
    float* __restrict__ se_sum,          // out: per (b,cout) sums (SE_SUM)
    const float* __restrict__ se_sums_in,// in: prev-block sums (HSE_IN>0)
    const float* __restrict__ se_w1, const float* __restrict__ se_b1,
    const float* __restrict__ se_w2, const float* __restrict__ se_b2,
    float inv_spatial)
{
    constexpr int WIN = HIN, WOUT = HOUT;
    constexpr int TH = ROWS_T * PPT;
    constexpr int IH_T = (TH - 1) * STRIDE + 3;
    constexpr int NW = NTHREADS / 64;
    constexpr int NCHUNK = CINB / CB;
    constexpr int SEGS = (WIN >= 64) ? (WIN / 64) : 1;
    constexpr int PAIRS = (IH_T + 1) / 2;
    static_assert(NTHREADS == TW * ROWS_T, "geometry");
    static_assert(TW == WOUT, "tile must span full output width");
    static_assert(CINB % CB == 0, "chunking");
    static_assert(COB % 4 == 0, "float4 weights");
    static_assert(WIN % 64 == 0 || WIN == 32, "stage width");

    const int b = blockIdx.z;
    const int gy = blockIdx.y;
    const int ty = blockIdx.x;
    const int tid = threadIdx.x;
    const int wo = tid % TW;
    const int rg = tid / TW;

    __shared__ __align__(16) float wl[CINB * 9 * COB];
    __shared__ float in_t[2][CB * IH_T * WIN];
    __shared__ float scl[CIN];
    __shared__ float gl[COB], bl[COB];
    __shared__ float red[NW][COB];
    __shared__ float hid[HSE_IN > 0 ? HSE_IN : 1];

    constexpr int NGRP = (KSPLIT == 2) ? 2 : 1;
    const int ng = gridDim.y / NGRP;             // cout groups
    const int g = gy % ng;
    const int kk = gy / ng;
    const int cin0 = kk * CINB;

    const float* inb = in + (size_t)b * CIN * HIN * WIN;
    const int gr0 = ty * TH * STRIDE - 1;
    const int wos = wo * STRIDE;
    const int wvid = tid >> 6, lane = tid & 63;

    auto stage = [&](int c, int buf) {
        const int cb0 = cin0 + c * CB;
        float* bb = &in_t[buf][0];
        if (WIN >= 64) {
            for (int r = wvid; r < CB * IH_T; r += NW) {
                int ci = r / IH_T, lr = r - ci * IH_T;
                int gr = gr0 + lr;
                float* ldst = bb + (ci * IH_T + lr) * WIN;
                if (gr >= 0 && gr < HIN) {
                    const float* gsrc = inb + (size_t)(cb0 + ci) * HIN * WIN + (size_t)gr * WIN;
#pragma unroll
                    for (int s = 0; s < SEGS; ++s)
                        gload_lds4(gsrc + s * 64 + lane, ldst + s * 64);
                } else {
#pragma unroll
                    for (int s = 0; s < SEGS; ++s) ldst[s * 64 + lane] = 0.0f;
                }
            }
        } else {  // WIN == 32: row pairs per wave-load
            for (int pz = wvid; pz < CB * PAIRS; pz += NW) {
                int ci = pz / PAIRS, q = pz - ci * PAIRS;
                int lr0 = q * 2;
                int nr = (lr0 + 1 < IH_T) ? 2 : 1;
                int grr = gr0 + lr0;
                float* ldst = bb + (ci * IH_T + lr0) * WIN;
                if (nr == 2 && grr >= 0 && grr + 1 < HIN) {
                    const float* gsrc = inb + (size_t)(cb0 + ci) * HIN * WIN + (size_t)grr * WIN + lane;
                    gload_lds4(gsrc, ldst);
                } else {
                    for (int e = lane; e < nr * WIN; e += 64) {
                        int rr = e / WIN, cc = e - rr * WIN;
                        int gr = grr + rr;
                        ldst[e] = (gr >= 0 && gr < HIN)
                            ? inb[(size_t)(cb0 + ci) * HIN * WIN + (size_t)gr * WIN + cc] : 0.0f;
                    }
                }
            }
        }
    };

    stage(0, 0);  // chunk-0 DMA flies under SE-MLP + weight staging

    // ---- SE scale of previous block (per b, per cin) ----
    if (HSE_IN > 0) {
        if (tid < HSE_IN) {
            float a = se_b1[tid];
            for (int c = 0; c < CIN; ++c)
                a = fmaf(se_sums_in[b * CIN + c] * inv_spatial, se_w1[tid * CIN + c], a);
            hid[tid] = fmaxf(a, 0.0f);
        }
        __syncthreads();
        if (tid < CIN) {
            float a = se_b2[tid];
            for (int h = 0; h < HSE_IN; ++h)
                a = fmaf(hid[h], se_w2[tid * HSE_IN + h], a);
            scl[tid] = 1.0f / (1.0f + expf(-a));
        }
    } else {
        for (int t = tid; t < CIN; t += NTHREADS) scl[t] = 1.0f;
    }
    __syncthreads();  // scl visible

    // ---- weights (SE scale folded in) ----
    for (int t = tid; t < CINB * 9 * COB; t += NTHREADS) {
        int col = t % COB;
        int rk = t / COB;
        int cin = rk / 9, k = rk % 9;
        wl[t] = w[((size_t)(g * COB + col) * CIN + cin0 + cin) * 9 + k] * scl[cin0 + cin];
    }
    if (tid < COB) {
        int co = g * COB + tid;
        if (BN_RELU) {
            gl[tid] = gamma[co] * BN_INV_F;
            bl[tid] = beta[co];
        } else {
            gl[tid] = (KSPLIT == 2 && kk == 1) ? 0.0f : gamma[co];
        }
    }

    float acc[PPT][COB];
#pragma unroll
    for (int p = 0; p < PPT; ++p)
#pragma unroll
        for (int co = 0; co < COB; ++co) acc[p][co] = 0.0f;

    int cur = 0;
    for (int c = 0; c < NCHUNK; ++c) {
        asm volatile("s_waitcnt vmcnt(0)" ::: "memory");
        __syncthreads();  // buf[cur] staged; wl/scl visible (first iter)
        if (c + 1 < NCHUNK) stage(c + 1, cur ^ 1);

        const float* bb = &in_t[cur][0];
        for (int ci = 0; ci < CB; ++ci) {
            const int cw = c * CB + ci;
#pragma unroll
            for (int kh = 0; kh < 3; ++kh) {
#pragma unroll
                for (int kw = 0; kw < 3; ++kw) {
                    const float4* wrow4 = (const float4*)&wl[(cw * 9 + kh * 3 + kw) * COB];
                    float wv[COB];
#pragma unroll
                    for (int q = 0; q < COB / 4; ++q) {
                        float4 t = wrow4[q];
                        wv[q * 4 + 0] = t.x; wv[q * 4 + 1] = t.y;
                        wv[q * 4 + 2] = t.z; wv[q * 4 + 3] = t.w;
                    }
#pragma unroll
                    for (int p = 0; p < PPT; ++p) {
                        const float* row = bb + (ci * IH_T + (rg + p * ROWS_T) * STRIDE + kh) * WIN;
                        int wi = wos + kw - 1;
                        float v;
                        if (kw == 0) {
                            v = row[wi < 0 ? 0 : wi];
                            if (wi < 0) v = 0.0f;
                        } else if (STRIDE == 1 && kw == 2) {
                            v = row[wi >= WIN ? WIN - 1 : wi];
                            if (wi >= WIN) v = 0.0f;
                        } else {
                            v = row[wi];
                        }
#pragma unroll
                        for (int co = 0; co < COB; ++co)
                            acc[p][co] = fmaf(wv[co], v, acc[p][co]);
                    }
                }
            }
        }
        cur ^= 1;
    }

    // epilogue
    float tsum[COB];
#pragma unroll
    for (int co = 0; co < COB; ++co) tsum[co] = 0.0f;
    float* ob = ((KSPLIT == 2 && kk == 1) ? out2 : out)
         + ((size_t)b * (size_t)(ng * COB) + (size_t)g * COB) * HOUT * WOUT;
#pragma unroll
    for (int p = 0; p < PPT; ++p) {
        const int ho = ty * TH + rg + p * ROWS_T;
#pragma unroll
        for (int co = 0; co < COB; ++co) {
            float v;
            if (BN_RELU)
                v = fmaxf(fmaf(acc[p][co], gl[co], bl[co]), 0.0f);
            else
                v = acc[p][co] + gl[co];
            ob[(size_t)co * HOUT * WOUT + ho * WOUT + wo] = v;
            tsum[co] += v;
        }
    }

    if (SE_SUM) {
#pragma unroll
        for (int co = 0; co < COB; ++co) {
            float v = tsum[co];
            for (int off = 32; off; off >>= 1) v += __shfl_down(v, off, 64);
            if (lane == 0) red[wvid][co] = v;
        }
        __syncthreads();
        if (tid < COB) {
            float v = 0.0f;
#pragma unroll
            for (int k = 0; k < NW; ++k) v += red[k][tid];
            atomicAdd(&se_sum[b * (ng * COB) + g * COB + tid], v);
        }
    }
}

// ---------------------------------------------------------------------------
// Capsule squash over sum of two partial buffers.
// ---------------------------------------------------------------------------
__global__ __launch_bounds__(256) void squash2_k(const float* __restrict__ ua,
                                                 const float* __restrict__ ub,
                                                 float* __restrict__ u)
{
    const int idx = blockIdx.x * 256 + threadIdx.x;  // b*2048 + i
    const int b = idx >> 11, i = idx & 2047;
    const int chi = i >> 8, spx = i & 255;
    const size_t off = ((size_t)(b * 64 + chi * 8)) * 256 + spx;
    float s[8];
    float n2 = 0.0f;
#pragma unroll
    for (int j = 0; j < 8; j++) {
        s[j] = ua[off + (size_t)j * 256] + ub[off + (size_t)j * 256];
        n2 = fmaf(s[j], s[j], n2);
    }
    const float n = sqrtf(n2);
    const float f = (n2 / (1.0f + n2)) / (n + 1e-8f);
    float* q = u + (size_t)idx * 8;
#pragma unroll
    for (int j = 0; j < 8; j++) q[j] = s[j] * f;
}

// ---------------------------------------------------------------------------
// u_hat[b,i,c,d] = sum_e W[i,c,d,e] * u[b,i,e]
// ---------------------------------------------------------------------------
__global__ __launch_bounds__(256) void uhat_k(const float* __restrict__ u,
                                              const float* __restrict__ W,
                                              float* __restrict__ u_hat)
{
    const int idx = blockIdx.x * 256 + threadIdx.x;  // (b*2048+i)*48 + cd
    const int cd = idx % 48;
    const int bi = idx / 48;
    const int i = bi & 2047;
    const float* uu = u + (size_t)bi * 8;
    const float* wp = W + (size_t)i * 384 + cd * 8;
    float a = 0.0f;
#pragma unroll
    for (int e = 0; e < 8; e++) a = fmaf(wp[e], uu[e], a);
    u_hat[idx] = a;
}

// ---------------------------------------------------------------------------
// Routing sweep IT (0..2). b_ij recomputed from stored s-history:
//   b_ij = sum_{t<IT} dot(u_hat_i[j], squash(s^(t))[j])
// grid = (8, 64): blockIdx.y = batch, 256 caps/block, 1 cap/thread.
// Partial s_j accumulated: wave shuffle -> LDS -> 48 atomicAdds.
// ---------------------------------------------------------------------------
template <int IT>
__global__ __launch_bounds__(256) void sweep_k(const float* __restrict__ u_hat,
                                               const float* __restrict__ s_hist,
                                               float* __restrict__ s_out)
{
    const int b = blockIdx.y;
    const int i = blockIdx.x * 256 + threadIdx.x;
    const int tid = threadIdx.x;
    __shared__ float vsh[IT > 0 ? IT : 1][48];
    __shared__ float fac[IT > 0 ? IT : 1][3];
    __shared__ float red[4][48];

    // issue u_hat loads early (independent of LDS staging below)
    const float4* qp = (const float4*)(u_hat + ((size_t)b * 2048 + i) * 48);
    float uhv[48];
#pragma unroll
    for (int q = 0; q < 12; ++q) {
        float4 t = qp[q];
        uhv[q * 4 + 0] = t.x; uhv[q * 4 + 1] = t.y;
        uhv[q * 4 + 2] = t.z; uhv[q * 4 + 3] = t.w;
    }

    if (IT > 0) {
        if (tid < IT * 48) {
            int t = tid / 48, c = tid % 48;
            vsh[t][c] = s_hist[((size_t)t * 64 + b) * 48 + c];
        }
        __syncthreads();
        if (tid < IT * 3) {
            int t = tid / 3, j = tid % 3;
            float n2 = 0.0f;
            for (int d = 0; d < 16; ++d) { float s = vsh[t][j * 16 + d]; n2 = fmaf(s, s, n2); }
            float n = sqrtf(n2);
            fac[t][j] = (n2 / (1.0f + n2)) / (n + 1e-8f);
        }
        __syncthreads();
        if (tid < IT * 48) {
            int t = tid / 48, c = tid % 48;
            vsh[t][c] *= fac[t][c / 16];
        }
        __syncthreads();
    }

    float c0, c1, c2;
    if (IT == 0) {
        c0 = c1 = c2 = (1.0f / 3.0f);
    } else {
        float b0 = 0.0f, b1 = 0.0f, b2 = 0.0f;
#pragma unroll
        for (int t = 0; t < IT; ++t)
#pragma unroll
            for (int d = 0; d < 16; ++d) {
                b0 = fmaf(uhv[d],      vsh[t][d],      b0);
                b1 = fmaf(uhv[16 + d], vsh[t][16 + d], b1);
                b2 = fmaf(uhv[32 + d], vsh[t][32 + d], b2);
            }
        float m = fmaxf(b0, fmaxf(b1, b2));
        float e0 = expf(b0 - m), e1 = expf(b1 - m), e2 = expf(b2 - m);
        float inv = 1.0f / (e0 + e1 + e2);
        c0 = e0 * inv; c1 = e1 * inv; c2 = e2 * inv;
    }

    float sp[48];
#pragma unroll
    for (int d = 0; d < 16; ++d) {
        sp[d]      = c0 * uhv[d];
        sp[16 + d] = c1 * uhv[16 + d];
        sp[32 + d] = c2 * uhv[32 + d];
    }
    const int lane = tid & 63, wv = tid >> 6;
#pragma unroll
    for (int j = 0; j < 48; ++j) {
        float x = sp[j];
        for (int off = 32; off; off >>= 1) x += __shfl_down(x, off, 64);
        if (lane == 0) red[wv][j] = x;
    }
    __syncthreads();
    if (tid < 48) {
        float x = red[0][tid] + red[1][tid] + red[2][tid] + red[3][tid];
        atomicAdd(&s_out[(size_t)b * 48 + tid], x);
    }
}

// ---------------------------------------------------------------------------
// out[b][j] = || squash(s2[b])[j] || = fac_j * n_j
// ---------------------------------------------------------------------------
__global__ __launch_bounds__(64) void route_out_k(const float* __restrict__ s2,
                                                  float* __restrict__ out)
{
    const int b = blockIdx.x;
    __shared__ float s[48];
    if (threadIdx.x < 48) s[threadIdx.x] = s2[(size_t)b * 48 + threadIdx.x];
    __syncthreads();
    if (threadIdx.x < 3) {
        int j = threadIdx.x;
        float n2 = 0.0f;
        for (int d = 0; d < 16; ++d) { float v = s[j * 16 + d]; n2 = fmaf(v, v, n2); }
        float n = sqrtf(n2);
        float fc = (n2 / (1.0f + n2)) / (n + 1e-8f);
        out[b * 3 + j] = fc * n;
    }
}

// ---------------------------------------------------------------------------
extern "C" void kernel_launch(void* const* d_in, const int* in_sizes, int n_in,
                              void* d_out, int out_size, void* d_ws, size_t ws_size,
                              hipStream_t stream)
{
    const float* x       = (const float*)d_in[0];
    const float* conv1_w = (const float*)d_in[1];
    const float* bn1_g   = (const float*)d_in[2];
    const float* bn1_b   = (const float*)d_in[3];
    const float* se1_w1  = (const float*)d_in[4];
    const float* se1_b1  = (const float*)d_in[5];
    const float* se1_w2  = (const float*)d_in[6];
    const float* se1_b2  = (const float*)d_in[7];
    const float* conv2_w = (const float*)d_in[8];
    const float* bn2_g   = (const float*)d_in[9];
    const float* bn2_b   = (const float*)d_in[10];
    const float* se2_w1  = (const float*)d_in[11];
    const float* se2_b1  = (const float*)d_in[12];
    const float* se2_w2  = (const float*)d_in[13];
    const float* se2_b2  = (const float*)d_in[14];
    const float* conv3_w = (const float*)d_in[15];
    const float* bn3_g   = (const float*)d_in[16];
    const float* bn3_b   = (const float*)d_in[17];
    const float* se3_w1  = (const float*)d_in[18];
    const float* se3_b1  = (const float*)d_in[19];
    const float* se3_w2  = (const float*)d_in[20];
    const float* se3_b2  = (const float*)d_in[21];
    const float* pc_w    = (const float*)d_in[22];
    const float* pc_b    = (const float*)d_in[23];
    const float* W_digit = (const float*)d_in[24];  // (1,2048,3,16,8)

    float* ws = (float*)d_ws;
    float* h1     = ws;                  // (64,16,128,128)
    float* h2     = ws + 16777216;       // (64,32,64,64)
    float* h3     = ws;                  // (64,64,32,32)  (overlays dead h1)
    float* u_rawA = ws + 4194304;        // (64,64,16,16)
    float* u      = ws + 5242880;        // (64,2048,8)
    float* u_hat  = ws + 6291456;        // (64,2048,48)
    float* u_rawB = ws + 12582912;       // (64,64,16,16) second partial
    float* sums   = ws + 25165824;       // [s1 1024][s2 2048][s3 4096]
    float* s1 = sums, *s2 = sums + 1024, *s3 = sums + 3072;
    float* s_buf  = sums + 7168;         // 3 x (64 x 48) routing s accumulators

    hipMemsetAsync(sums, 0, 16384 * sizeof(float), stream);

    // conv1: 1->16, 128x128, s1. TW=128, ROWS_T=2, PPT=2 (TH=4), CB=1.
    convt_k<1, 1, 16, 128, 128, 1, 128, 2, 2, 1, 256, true, true, 0, 1>
        <<<dim3(32, 1, 64), 256, 0, stream>>>(
            x, conv1_w, bn1_g, bn1_b, h1, nullptr, s1,
            nullptr, nullptr, nullptr, nullptr, nullptr, 0.0f);

    // conv2: 16->32, ->64x64, s2. COB=32 (g=1). TW=64, ROWS_T=4, PPT=2 (TH=8), CB=2.
    convt_k<16, 16, 32, 128, 64, 2, 64, 4, 2, 2, 256, true, true, 1, 1>
        <<<dim3(8, 1, 64), 256, 0, stream>>>(
            h1, conv2_w, bn2_g, bn2_b, h2, nullptr, s2,
            s1, se1_w1, se1_b1, se1_w2, se1_b2, 1.0f / 16384.0f);

    // conv3: 32->64, ->32x32, s2. COB=16 (g=4). TW=32, ROWS_T=8, PPT=2 (TH=16), CB=2.
    convt_k<32, 32, 16, 64, 32, 2, 32, 8, 2, 2, 256, true, true, 2, 1>
        <<<dim3(2, 4, 64), 256, 0, stream>>>(
            h2, conv3_w, bn3_g, bn3_b, h3, nullptr, s3,
            s2, se2_w1, se2_b1, se2_w2, se2_b2, 1.0f / 4096.0f);

    // primary caps: 64->64, ->16x16, s2, +bias. COB=16 (g=4), CIN split x2.
    convt_k<64, 32, 16, 32, 16, 2, 16, 16, 1, 2, 256, false, false, 4, 2>
        <<<dim3(1, 8, 64), 256, 0, stream>>>(
            h3, pc_w, pc_b, nullptr, u_rawA, u_rawB, nullptr,
            s3, se3_w1, se3_b1, se3_w2, se3_b2, 1.0f / 1024.0f);

    squash2_k<<<512, 256, 0, stream>>>(u_rawA, u_rawB, u);
    uhat_k<<<24576, 256, 0, stream>>>(u, W_digit, u_hat);

    // routing: 3 parallel sweeps + final norm
    sweep_k<0><<<dim3(8, 64), 256, 0, stream>>>(u_hat, s_buf, s_buf + 0 * 64 * 48);
    sweep_k<1><<<dim3(8, 64), 256, 0, stream>>>(u_hat, s_buf, s_buf + 1 * 64 * 48);
    sweep_k<2><<<dim3(8, 64), 256, 0, stream>>>(u_hat, s_buf, s_buf + 2 * 64 * 48);
    route_out_k<<<64, 64, 0, stream>>>(s_buf + 2 * 64 * 48, (float*)d_out);
}

// Round 7
// 236.103 us; speedup vs baseline: 2.5658x; 1.1854x over previous
//
#include <hip/hip_runtime.h>
#include <math.h>

#define BN_INV_F 0.9999950000374997f

__device__ __forceinline__ void gload_lds4(const float* g, float* l) {
    __builtin_amdgcn_global_load_lds(
        (const __attribute__((address_space(1))) void*)g,
        (__attribute__((address_space(3))) void*)l, 4, 0, 0);
}

// ---------------------------------------------------------------------------
// Weight transpose (once, all four convs): wt[(cin*9+k)*COUT + co] = w[co][cin][k]
// Segments: w1 144 | w2 4608 | w3 18432 | wp 36864  (total 60048)
// ---------------------------------------------------------------------------
__global__ __launch_bounds__(256) void wtrans_all_k(
    const float* __restrict__ w1, const float* __restrict__ w2,
    const float* __restrict__ w3, const float* __restrict__ wp,
    float* __restrict__ w1t, float* __restrict__ w2t,
    float* __restrict__ w3t, float* __restrict__ wpt)
{
    int i = blockIdx.x * 256 + threadIdx.x;
    if (i < 144) {
        int co = i % 16, k = i / 16;
        w1t[i] = w1[co * 9 + k];
    } else if (i < 4752) {
        int t = i - 144;
        int co = t % 32, rk = t / 32, cin = rk / 9, k = rk % 9;
        w2t[t] = w2[(co * 16 + cin) * 9 + k];
    } else if (i < 23184) {
        int t = i - 4752;
        int co = t % 64, rk = t / 64, cin = rk / 9, k = rk % 9;
        w3t[t] = w3[(co * 32 + cin) * 9 + k];
    } else if (i < 60048) {
        int t = i - 23184;
        int co = t % 64, rk = t / 64, cin = rk / 9, k = rk % 9;
        wpt[t] = wp[(co * 64 + cin) * 9 + k];
    }
}

// ---------------------------------------------------------------------------
// LDS-staged tiled direct 3x3 conv, pad=1, full-width tiles (TW == WOUT).
//  - input staged via global_load_lds (dbuf chunks); weights read from GLOBAL
//    via wave-uniform addresses -> s_load -> SGPR operand of v_fmac (no LDS)
//  - SE scale of previous block computed in-kernel, applied to input value v
//  - optional CIN split (KSPLIT>1): out + kk*pstride partial buffers
// grid = (HOUT/(ROWS_T*PPT), (COUT/COB)*KSPLIT, B), block = TW*ROWS_T
// ---------------------------------------------------------------------------
template <int CIN, int CINB, int COUT, int COB, int HIN, int HOUT, int STRIDE,
          int TW, int ROWS_T, int PPT, int CB, int NTHREADS,
          bool BN_RELU, bool SE_SUM, int HSE_IN, int KSPLIT>
__global__ __launch_bounds__(NTHREADS) void convt_k(
    const float* __restrict__ in, const float* __restrict__ wt,
    const float* __restrict__ gamma,     // BN gamma (BN_RELU) or bias
    const float* __restrict__ beta,      // BN beta  (BN_RELU) or unused
    float* __restrict__ out, size_t pstride,
    float* __restrict__ se_sum,          // out: per (b,cout) sums (SE_SUM)
    const float* __restrict__ se_sums_in,// in: prev-block sums (HSE_IN>0)
    const float* __restrict__ se_w1, const float* __restrict__ se_b1,
    const float* __restrict__ se_w2, const float* __restrict__ se_b2,
    float inv_spatial)
{
    constexpr int WIN = HIN, WOUT = HOUT;
    constexpr int TH = ROWS_T * PPT;
    constexpr int IH_T = (TH - 1) * STRIDE + 3;
    constexpr int NW = NTHREADS / 64;
    constexpr int NCHUNK = CINB / CB;
    constexpr int SEGS = (WIN >= 64) ? (WIN / 64) : 1;
    constexpr int PAIRS = (IH_T + 1) / 2;
    constexpr int NG = COUT / COB;
    static_assert(NTHREADS == TW * ROWS_T, "geometry");
    static_assert(TW == WOUT, "tile must span full output width");
    static_assert(CINB % CB == 0, "chunking");
    static_assert(WIN % 64 == 0 || WIN == 32, "stage width");

    const int b = blockIdx.z;
    const int gy = blockIdx.y;
    const int ty = blockIdx.x;
    const int tid = threadIdx.x;
    const int wo = tid % TW;
    const int rg = tid / TW;
    const int g = gy % NG;
    const int kk = gy / NG;
    const int cin0 = kk * CINB;

    __shared__ float in_t[2][CB * IH_T * WIN];
    __shared__ float scl[CIN];
    __shared__ float gl[COB], bl[COB];
    __shared__ float red[NW][COB];
    __shared__ float hid[HSE_IN > 0 ? HSE_IN : 1];

    const float* inb = in + (size_t)b * CIN * HIN * WIN;
    const int gr0 = ty * TH * STRIDE - 1;
    const int wos = wo * STRIDE;
    const int wvid = tid >> 6, lane = tid & 63;

    auto stage = [&](int c, int buf) {
        const int cb0 = cin0 + c * CB;
        float* bb = &in_t[buf][0];
        if (WIN >= 64) {
            for (int r = wvid; r < CB * IH_T; r += NW) {
                int ci = r / IH_T, lr = r - ci * IH_T;
                int gr = gr0 + lr;
                float* ldst = bb + (ci * IH_T + lr) * WIN;
                if (gr >= 0 && gr < HIN) {
                    const float* gsrc = inb + (size_t)(cb0 + ci) * HIN * WIN + (size_t)gr * WIN;
#pragma unroll
                    for (int s = 0; s < SEGS; ++s)
                        gload_lds4(gsrc + s * 64 + lane, ldst + s * 64);
                } else {
#pragma unroll
                    for (int s = 0; s < SEGS; ++s) ldst[s * 64 + lane] = 0.0f;
                }
            }
        } else {  // WIN == 32: row pairs per wave-load
            for (int pz = wvid; pz < CB * PAIRS; pz += NW) {
                int ci = pz / PAIRS, q = pz - ci * PAIRS;
                int lr0 = q * 2;
                int nr = (lr0 + 1 < IH_T) ? 2 : 1;
                int grr = gr0 + lr0;
                float* ldst = bb + (ci * IH_T + lr0) * WIN;
                if (nr == 2 && grr >= 0 && grr + 1 < HIN) {
                    const float* gsrc = inb + (size_t)(cb0 + ci) * HIN * WIN + (size_t)grr * WIN + lane;
                    gload_lds4(gsrc, ldst);
                } else {
                    for (int e = lane; e < nr * WIN; e += 64) {
                        int rr = e / WIN, cc = e - rr * WIN;
                        int gr = grr + rr;
                        ldst[e] = (gr >= 0 && gr < HIN)
                            ? inb[(size_t)(cb0 + ci) * HIN * WIN + (size_t)gr * WIN + cc] : 0.0f;
                    }
                }
            }
        }
    };

    stage(0, 0);  // chunk-0 DMA flies under SE-MLP

    // ---- SE scale of previous block (per b, per cin) ----
    if (HSE_IN > 0) {
        if (tid < HSE_IN) {
            float a = se_b1[tid];
            for (int c = 0; c < CIN; ++c)
                a = fmaf(se_sums_in[b * CIN + c] * inv_spatial, se_w1[tid * CIN + c], a);
            hid[tid] = fmaxf(a, 0.0f);
        }
        __syncthreads();
        if (tid < CIN) {
            float a = se_b2[tid];
            for (int h = 0; h < HSE_IN; ++h)
                a = fmaf(hid[h], se_w2[tid * HSE_IN + h], a);
            scl[tid] = 1.0f / (1.0f + expf(-a));
        }
    } else {
        for (int t = tid; t < CIN; t += NTHREADS) scl[t] = 1.0f;
    }
    if (tid < COB) {
        int co = g * COB + tid;
        if (BN_RELU) {
            gl[tid] = gamma[co] * BN_INV_F;
            bl[tid] = beta[co];
        } else {
            gl[tid] = (kk == 0) ? gamma[co] : 0.0f;
        }
    }

    float acc[PPT][COB];
#pragma unroll
    for (int p = 0; p < PPT; ++p)
#pragma unroll
        for (int co = 0; co < COB; ++co) acc[p][co] = 0.0f;

    int cur = 0;
    for (int c = 0; c < NCHUNK; ++c) {
        asm volatile("s_waitcnt vmcnt(0)" ::: "memory");
        __syncthreads();  // buf[cur] staged; scl/gl visible (first iter)
        if (c + 1 < NCHUNK) stage(c + 1, cur ^ 1);

        const float* bb = &in_t[cur][0];
        for (int ci = 0; ci < CB; ++ci) {
            const int cw = cin0 + c * CB + ci;      // global cin
            const float sc = scl[cw];
            const float* wtap = wt + (size_t)cw * 9 * COUT + g * COB;
#pragma unroll
            for (int kh = 0; kh < 3; ++kh) {
#pragma unroll
                for (int kw = 0; kw < 3; ++kw) {
                    const float* wrow = wtap + (kh * 3 + kw) * COUT;  // uniform -> SGPR
#pragma unroll
                    for (int p = 0; p < PPT; ++p) {
                        const float* row = bb + (ci * IH_T + (rg + p * ROWS_T) * STRIDE + kh) * WIN;
                        int wi = wos + kw - 1;
                        float v;
                        if (kw == 0) {
                            v = row[wi < 0 ? 0 : wi];
                            if (wi < 0) v = 0.0f;
                        } else if (STRIDE == 1 && kw == 2) {
                            v = row[wi >= WIN ? WIN - 1 : wi];
                            if (wi >= WIN) v = 0.0f;
                        } else {
                            v = row[wi];
                        }
                        v *= sc;
#pragma unroll
                        for (int co = 0; co < COB; ++co)
                            acc[p][co] = fmaf(wrow[co], v, acc[p][co]);
                    }
                }
            }
        }
        cur ^= 1;
    }

    // epilogue
    float tsum[COB];
#pragma unroll
    for (int co = 0; co < COB; ++co) tsum[co] = 0.0f;
    float* ob = out + (size_t)kk * pstride
              + ((size_t)b * COUT + (size_t)g * COB) * HOUT * WOUT;
#pragma unroll
    for (int p = 0; p < PPT; ++p) {
        const int ho = ty * TH + rg + p * ROWS_T;
#pragma unroll
        for (int co = 0; co < COB; ++co) {
            float v;
            if (BN_RELU)
                v = fmaxf(fmaf(acc[p][co], gl[co], bl[co]), 0.0f);
            else
                v = acc[p][co] + gl[co];
            ob[(size_t)co * HOUT * WOUT + ho * WOUT + wo] = v;
            tsum[co] += v;
        }
    }

    if (SE_SUM) {
#pragma unroll
        for (int co = 0; co < COB; ++co) {
            float v = tsum[co];
            for (int off = 32; off; off >>= 1) v += __shfl_down(v, off, 64);
            if (lane == 0) red[wvid][co] = v;
        }
        __syncthreads();
        if (tid < COB) {
            float v = 0.0f;
#pragma unroll
            for (int k = 0; k < NW; ++k) v += red[k][tid];
            atomicAdd(&se_sum[b * COUT + g * COB + tid], v);
        }
    }
}

// ---------------------------------------------------------------------------
// Capsule squash over sum of four partial buffers (u_parts + kk*pstride).
// ---------------------------------------------------------------------------
__global__ __launch_bounds__(256) void squash4_k(const float* __restrict__ up,
                                                 size_t pstride,
                                                 float* __restrict__ u)
{
    const int idx = blockIdx.x * 256 + threadIdx.x;  // b*2048 + i
    const int b = idx >> 11, i = idx & 2047;
    const int chi = i >> 8, spx = i & 255;
    const size_t off = ((size_t)(b * 64 + chi * 8)) * 256 + spx;
    float s[8];
    float n2 = 0.0f;
#pragma unroll
    for (int j = 0; j < 8; j++) {
        const size_t o = off + (size_t)j * 256;
        s[j] = (up[o] + up[o + pstride]) + (up[o + 2 * pstride] + up[o + 3 * pstride]);
        n2 = fmaf(s[j], s[j], n2);
    }
    const float n = sqrtf(n2);
    const float f = (n2 / (1.0f + n2)) / (n + 1e-8f);
    float* q = u + (size_t)idx * 8;
#pragma unroll
    for (int j = 0; j < 8; j++) q[j] = s[j] * f;
}

// ---------------------------------------------------------------------------
// u_hat[b,i,c,d] = sum_e W[i,c,d,e] * u[b,i,e]
// ---------------------------------------------------------------------------
__global__ __launch_bounds__(256) void uhat_k(const float* __restrict__ u,
                                              const float* __restrict__ W,
                                              float* __restrict__ u_hat)
{
    const int idx = blockIdx.x * 256 + threadIdx.x;  // (b*2048+i)*48 + cd
    const int cd = idx % 48;
    const int bi = idx / 48;
    const int i = bi & 2047;
    const float* uu = u + (size_t)bi * 8;
    const float* wp = W + (size_t)i * 384 + cd * 8;
    float a = 0.0f;
#pragma unroll
    for (int e = 0; e < 8; e++) a = fmaf(wp[e], uu[e], a);
    u_hat[idx] = a;
}

// ---------------------------------------------------------------------------
// Routing sweep IT (0..2). b_ij recomputed from stored s-history:
//   b_ij = sum_{t<IT} dot(u_hat_i[j], squash(s^(t))[j])
// grid = (8, 64): blockIdx.y = batch, 256 caps/block, 1 cap/thread.
// ---------------------------------------------------------------------------
template <int IT>
__global__ __launch_bounds__(256) void sweep_k(const float* __restrict__ u_hat,
                                               const float* __restrict__ s_hist,
                                               float* __restrict__ s_out)
{
    const int b = blockIdx.y;
    const int i = blockIdx.x * 256 + threadIdx.x;
    const int tid = threadIdx.x;
    __shared__ float vsh[IT > 0 ? IT : 1][48];
    __shared__ float fac[IT > 0 ? IT : 1][3];
    __shared__ float red[4][48];

    const float4* qp = (const float4*)(u_hat + ((size_t)b * 2048 + i) * 48);
    float uhv[48];
#pragma unroll
    for (int q = 0; q < 12; ++q) {
        float4 t = qp[q];
        uhv[q * 4 + 0] = t.x; uhv[q * 4 + 1] = t.y;
        uhv[q * 4 + 2] = t.z; uhv[q * 4 + 3] = t.w;
    }

    if (IT > 0) {
        if (tid < IT * 48) {
            int t = tid / 48, c = tid % 48;
            vsh[t][c] = s_hist[((size_t)t * 64 + b) * 48 + c];
        }
        __syncthreads();
        if (tid < IT * 3) {
            int t = tid / 3, j = tid % 3;
            float n2 = 0.0f;
            for (int d = 0; d < 16; ++d) { float s = vsh[t][j * 16 + d]; n2 = fmaf(s, s, n2); }
            float n = sqrtf(n2);
            fac[t][j] = (n2 / (1.0f + n2)) / (n + 1e-8f);
        }
        __syncthreads();
        if (tid < IT * 48) {
            int t = tid / 48, c = tid % 48;
            vsh[t][c] *= fac[t][c / 16];
        }
        __syncthreads();
    }

    float c0, c1, c2;
    if (IT == 0) {
        c0 = c1 = c2 = (1.0f / 3.0f);
    } else {
        float b0 = 0.0f, b1 = 0.0f, b2 = 0.0f;
#pragma unroll
        for (int t = 0; t < IT; ++t)
#pragma unroll
            for (int d = 0; d < 16; ++d) {
                b0 = fmaf(uhv[d],      vsh[t][d],      b0);
                b1 = fmaf(uhv[16 + d], vsh[t][16 + d], b1);
                b2 = fmaf(uhv[32 + d], vsh[t][32 + d], b2);
            }
        float m = fmaxf(b0, fmaxf(b1, b2));
        float e0 = expf(b0 - m), e1 = expf(b1 - m), e2 = expf(b2 - m);
        float inv = 1.0f / (e0 + e1 + e2);
        c0 = e0 * inv; c1 = e1 * inv; c2 = e2 * inv;
    }

    float sp[48];
#pragma unroll
    for (int d = 0; d < 16; ++d) {
        sp[d]      = c0 * uhv[d];
        sp[16 + d] = c1 * uhv[16 + d];
        sp[32 + d] = c2 * uhv[32 + d];
    }
    const int lane = tid & 63, wv = tid >> 6;
#pragma unroll
    for (int j = 0; j < 48; ++j) {
        float x = sp[j];
        for (int off = 32; off; off >>= 1) x += __shfl_down(x, off, 64);
        if (lane == 0) red[wv][j] = x;
    }
    __syncthreads();
    if (tid < 48) {
        float x = red[0][tid] + red[1][tid] + red[2][tid] + red[3][tid];
        atomicAdd(&s_out[(size_t)b * 48 + tid], x);
    }
}

// ---------------------------------------------------------------------------
__global__ __launch_bounds__(64) void route_out_k(const float* __restrict__ s2,
                                                  float* __restrict__ out)
{
    const int b = blockIdx.x;
    __shared__ float s[48];
    if (threadIdx.x < 48) s[threadIdx.x] = s2[(size_t)b * 48 + threadIdx.x];
    __syncthreads();
    if (threadIdx.x < 3) {
        int j = threadIdx.x;
        float n2 = 0.0f;
        for (int d = 0; d < 16; ++d) { float v = s[j * 16 + d]; n2 = fmaf(v, v, n2); }
        float n = sqrtf(n2);
        float fc = (n2 / (1.0f + n2)) / (n + 1e-8f);
        out[b * 3 + j] = fc * n;
    }
}

// ---------------------------------------------------------------------------
extern "C" void kernel_launch(void* const* d_in, const int* in_sizes, int n_in,
                              void* d_out, int out_size, void* d_ws, size_t ws_size,
                              hipStream_t stream)
{
    const float* x       = (const float*)d_in[0];
    const float* conv1_w = (const float*)d_in[1];
    const float* bn1_g   = (const float*)d_in[2];
    const float* bn1_b   = (const float*)d_in[3];
    const float* se1_w1  = (const float*)d_in[4];
    const float* se1_b1  = (const float*)d_in[5];
    const float* se1_w2  = (const float*)d_in[6];
    const float* se1_b2  = (const float*)d_in[7];
    const float* conv2_w = (const float*)d_in[8];
    const float* bn2_g   = (const float*)d_in[9];
    const float* bn2_b   = (const float*)d_in[10];
    const float* se2_w1  = (const float*)d_in[11];
    const float* se2_b1  = (const float*)d_in[12];
    const float* se2_w2  = (const float*)d_in[13];
    const float* se2_b2  = (const float*)d_in[14];
    const float* conv3_w = (const float*)d_in[15];
    const float* bn3_g   = (const float*)d_in[16];
    const float* bn3_b   = (const float*)d_in[17];
    const float* se3_w1  = (const float*)d_in[18];
    const float* se3_b1  = (const float*)d_in[19];
    const float* se3_w2  = (const float*)d_in[20];
    const float* se3_b2  = (const float*)d_in[21];
    const float* pc_w    = (const float*)d_in[22];
    const float* pc_b    = (const float*)d_in[23];
    const float* W_digit = (const float*)d_in[24];  // (1,2048,3,16,8)

    float* ws = (float*)d_ws;
    // float-offset layout:
    //  [0,16777216)      h1 (64,16,128,128); after conv2: h3 overlays [0,4194304)
    //  [4194304,8388608) u_parts: 4 x 1048576 (64,64,16,16) partials
    //  [8388608,9437184) u (64,2048,8)
    //  [9437184,15728640) u_hat (64,2048,48)
    //  [16777216,25165824) h2 (64,32,64,64)
    //  [25165824,+7168)  SE sums  [s1 1024][s2 2048][s3 4096]
    //  [+7168,+16384)    s_buf (3 x 64 x 48)
    //  [25182208,...)    transposed weights w1t(144) w2t(4608) w3t(18432) wpt(36864)
    float* h1     = ws;
    float* h2     = ws + 16777216;
    float* h3     = ws;
    float* uparts = ws + 4194304;
    float* u      = ws + 8388608;
    float* u_hat  = ws + 9437184;
    float* sums   = ws + 25165824;
    float* s1 = sums, *s2 = sums + 1024, *s3 = sums + 3072;
    float* s_buf  = sums + 7168;
    float* w1t    = ws + 25182208;
    float* w2t    = w1t + 144;
    float* w3t    = w2t + 4608;
    float* wpt    = w3t + 18432;

    hipMemsetAsync(sums, 0, 16384 * sizeof(float), stream);
    wtrans_all_k<<<235, 256, 0, stream>>>(conv1_w, conv2_w, conv3_w, pc_w,
                                          w1t, w2t, w3t, wpt);

    // conv1: 1->16, 128x128, s1. TW=128, ROWS_T=2, PPT=2 (TH=4), CB=1. 2048 blocks.
    convt_k<1, 1, 16, 16, 128, 128, 1, 128, 2, 2, 1, 256, true, true, 0, 1>
        <<<dim3(32, 1, 64), 256, 0, stream>>>(
            x, w1t, bn1_g, bn1_b, h1, 0, s1,
            nullptr, nullptr, nullptr, nullptr, nullptr, 0.0f);

    // conv2: 16->32, ->64x64, s2. COB=32 (g=1). TW=64, ROWS_T=4, PPT=1 (TH=4), CB=2. 1024 blocks.
    convt_k<16, 16, 32, 32, 128, 64, 2, 64, 4, 1, 2, 256, true, true, 1, 1>
        <<<dim3(16, 1, 64), 256, 0, stream>>>(
            h1, w2t, bn2_g, bn2_b, h2, 0, s2,
            s1, se1_w1, se1_b1, se1_w2, se1_b2, 1.0f / 16384.0f);

    // conv3: 32->64, ->32x32, s2. COB=16 (g=4). TW=32, ROWS_T=8, PPT=1 (TH=8), CB=2. 1024 blocks.
    convt_k<32, 32, 64, 16, 64, 32, 2, 32, 8, 1, 2, 256, true, true, 2, 1>
        <<<dim3(4, 4, 64), 256, 0, stream>>>(
            h2, w3t, bn3_g, bn3_b, h3, 0, s3,
            s2, se2_w1, se2_b1, se2_w2, se2_b2, 1.0f / 4096.0f);

    // primary caps: 64->64, ->16x16, s2, +bias. COB=16 (g=4), KSPLIT=4 (CINB=16). 1024 blocks.
    convt_k<64, 16, 64, 16, 32, 16, 2, 16, 16, 1, 2, 256, false, false, 4, 4>
        <<<dim3(1, 16, 64), 256, 0, stream>>>(
            h3, wpt, pc_b, nullptr, uparts, (size_t)1048576, nullptr,
            s3, se3_w1, se3_b1, se3_w2, se3_b2, 1.0f / 1024.0f);

    squash4_k<<<512, 256, 0, stream>>>(uparts, (size_t)1048576, u);
    uhat_k<<<24576, 256, 0, stream>>>(u, W_digit, u_hat);

    sweep_k<0><<<dim3(8, 64), 256, 0, stream>>>(u_hat, s_buf, s_buf + 0 * 64 * 48);
    sweep_k<1><<<dim3(8, 64), 256, 0, stream>>>(u_hat, s_buf, s_buf + 1 * 64 * 48);
    sweep_k<2><<<dim3(8, 64), 256, 0, stream>>>(u_hat, s_buf, s_buf + 2 * 64 * 48);
    route_out_k<<<64, 64, 0, stream>>>(s_buf + 2 * 64 * 48, (float*)d_out);
}

// Round 8
// 228.665 us; speedup vs baseline: 2.6493x; 1.0325x over previous
//
#include <hip/hip_runtime.h>
#include <math.h>

#define BN_INV_F 0.9999950000374997f

__device__ __forceinline__ void gload_lds4(const float* g, float* l) {
    __builtin_amdgcn_global_load_lds(
        (const __attribute__((address_space(1))) void*)g,
        (__attribute__((address_space(3))) void*)l, 4, 0, 0);
}

// ---------------------------------------------------------------------------
// Weight transpose (once): wt[(cin*9+k)*COUT + co] = w[co][cin][k]
// ---------------------------------------------------------------------------
__global__ __launch_bounds__(256) void wtrans_all_k(
    const float* __restrict__ w1, const float* __restrict__ w2,
    const float* __restrict__ w3, const float* __restrict__ wp,
    float* __restrict__ w1t, float* __restrict__ w2t,
    float* __restrict__ w3t, float* __restrict__ wpt)
{
    int i = blockIdx.x * 256 + threadIdx.x;
    if (i < 144) {
        int co = i % 16, k = i / 16;
        w1t[i] = w1[co * 9 + k];
    } else if (i < 4752) {
        int t = i - 144;
        int co = t % 32, rk = t / 32, cin = rk / 9, k = rk % 9;
        w2t[t] = w2[(co * 16 + cin) * 9 + k];
    } else if (i < 23184) {
        int t = i - 4752;
        int co = t % 64, rk = t / 64, cin = rk / 9, k = rk % 9;
        w3t[t] = w3[(co * 32 + cin) * 9 + k];
    } else if (i < 60048) {
        int t = i - 23184;
        int co = t % 64, rk = t / 64, cin = rk / 9, k = rk % 9;
        wpt[t] = wp[(co * 64 + cin) * 9 + k];
    }
}

// ---------------------------------------------------------------------------
// LDS-staged tiled direct 3x3 conv, pad=1, full-width tiles (TW == WOUT).
// Weights via wave-uniform global reads (SGPR). SE scale applied to input.
// KSPLIT>1: raw partials (no BN) to out + kk*pstride.
// ---------------------------------------------------------------------------
template <int CIN, int CINB, int COUT, int COB, int HIN, int HOUT, int STRIDE,
          int TW, int ROWS_T, int PPT, int CB, int NTHREADS,
          bool BN_RELU, bool SE_SUM, int HSE_IN, int KSPLIT>
__global__ __launch_bounds__(NTHREADS) void convt_k(
    const float* __restrict__ in, const float* __restrict__ wt,
    const float* __restrict__ gamma,     // BN gamma (BN_RELU) or bias
    const float* __restrict__ beta,      // BN beta  (BN_RELU) or unused
    float* __restrict__ out, size_t pstride,
    float* __restrict__ se_sum,
    const float* __restrict__ se_sums_in,
    const float* __restrict__ se_w1, const float* __restrict__ se_b1,
    const float* __restrict__ se_w2, const float* __restrict__ se_b2,
    float inv_spatial)
{
    constexpr int WIN = HIN, WOUT = HOUT;
    constexpr int TH = ROWS_T * PPT;
    constexpr int IH_T = (TH - 1) * STRIDE + 3;
    constexpr int NW = NTHREADS / 64;
    constexpr int NCHUNK = CINB / CB;
    constexpr int SEGS = (WIN >= 64) ? (WIN / 64) : 1;
    constexpr int PAIRS = (IH_T + 1) / 2;
    constexpr int NG = COUT / COB;
    static_assert(NTHREADS == TW * ROWS_T, "geometry");
    static_assert(TW == WOUT, "tile must span full output width");
    static_assert(CINB % CB == 0, "chunking");
    static_assert(WIN % 64 == 0 || WIN == 32, "stage width");

    const int b = blockIdx.z;
    const int gy = blockIdx.y;
    const int ty = blockIdx.x;
    const int tid = threadIdx.x;
    const int wo = tid % TW;
    const int rg = tid / TW;
    const int g = gy % NG;
    const int kk = gy / NG;
    const int cin0 = kk * CINB;

    __shared__ float in_t[2][CB * IH_T * WIN];
    __shared__ float scl[CIN];
    __shared__ float gl[COB], bl[COB];
    __shared__ float red[NW][COB];
    __shared__ float hid[HSE_IN > 0 ? HSE_IN : 1];

    const float* inb = in + (size_t)b * CIN * HIN * WIN;
    const int gr0 = ty * TH * STRIDE - 1;
    const int wos = wo * STRIDE;
    const int wvid = tid >> 6, lane = tid & 63;

    auto stage = [&](int c, int buf) {
        const int cb0 = cin0 + c * CB;
        float* bb = &in_t[buf][0];
        if (WIN >= 64) {
            for (int r = wvid; r < CB * IH_T; r += NW) {
                int ci = r / IH_T, lr = r - ci * IH_T;
                int gr = gr0 + lr;
                float* ldst = bb + (ci * IH_T + lr) * WIN;
                if (gr >= 0 && gr < HIN) {
                    const float* gsrc = inb + (size_t)(cb0 + ci) * HIN * WIN + (size_t)gr * WIN;
#pragma unroll
                    for (int s = 0; s < SEGS; ++s)
                        gload_lds4(gsrc + s * 64 + lane, ldst + s * 64);
                } else {
#pragma unroll
                    for (int s = 0; s < SEGS; ++s) ldst[s * 64 + lane] = 0.0f;
                }
            }
        } else {  // WIN == 32: row pairs per wave-load
            for (int pz = wvid; pz < CB * PAIRS; pz += NW) {
                int ci = pz / PAIRS, q = pz - ci * PAIRS;
                int lr0 = q * 2;
                int nr = (lr0 + 1 < IH_T) ? 2 : 1;
                int grr = gr0 + lr0;
                float* ldst = bb + (ci * IH_T + lr0) * WIN;
                if (nr == 2 && grr >= 0 && grr + 1 < HIN) {
                    const float* gsrc = inb + (size_t)(cb0 + ci) * HIN * WIN + (size_t)grr * WIN + lane;
                    gload_lds4(gsrc, ldst);
                } else {
                    for (int e = lane; e < nr * WIN; e += 64) {
                        int rr = e / WIN, cc = e - rr * WIN;
                        int gr = grr + rr;
                        ldst[e] = (gr >= 0 && gr < HIN)
                            ? inb[(size_t)(cb0 + ci) * HIN * WIN + (size_t)gr * WIN + cc] : 0.0f;
                    }
                }
            }
        }
    };

    stage(0, 0);

    if (HSE_IN > 0) {
        if (tid < HSE_IN) {
            float a = se_b1[tid];
            for (int c = 0; c < CIN; ++c)
                a = fmaf(se_sums_in[b * CIN + c] * inv_spatial, se_w1[tid * CIN + c], a);
            hid[tid] = fmaxf(a, 0.0f);
        }
        __syncthreads();
        if (tid < CIN) {
            float a = se_b2[tid];
            for (int h = 0; h < HSE_IN; ++h)
                a = fmaf(hid[h], se_w2[tid * HSE_IN + h], a);
            scl[tid] = 1.0f / (1.0f + expf(-a));
        }
    } else {
        for (int t = tid; t < CIN; t += NTHREADS) scl[t] = 1.0f;
    }
    if (tid < COB) {
        int co = g * COB + tid;
        if (BN_RELU) {
            gl[tid] = gamma[co] * BN_INV_F;
            bl[tid] = beta[co];
        } else {
            gl[tid] = (kk == 0) ? gamma[co] : 0.0f;
        }
    }

    float acc[PPT][COB];
#pragma unroll
    for (int p = 0; p < PPT; ++p)
#pragma unroll
        for (int co = 0; co < COB; ++co) acc[p][co] = 0.0f;

    int cur = 0;
    for (int c = 0; c < NCHUNK; ++c) {
        asm volatile("s_waitcnt vmcnt(0)" ::: "memory");
        __syncthreads();
        if (c + 1 < NCHUNK) stage(c + 1, cur ^ 1);

        const float* bb = &in_t[cur][0];
        for (int ci = 0; ci < CB; ++ci) {
            const int cw = cin0 + c * CB + ci;
            const float sc = scl[cw];
            const float* wtap = wt + (size_t)cw * 9 * COUT + g * COB;
#pragma unroll
            for (int kh = 0; kh < 3; ++kh) {
#pragma unroll
                for (int kw = 0; kw < 3; ++kw) {
                    const float* wrow = wtap + (kh * 3 + kw) * COUT;  // uniform -> SGPR
#pragma unroll
                    for (int p = 0; p < PPT; ++p) {
                        const float* row = bb + (ci * IH_T + (rg + p * ROWS_T) * STRIDE + kh) * WIN;
                        int wi = wos + kw - 1;
                        float v;
                        if (kw == 0) {
                            v = row[wi < 0 ? 0 : wi];
                            if (wi < 0) v = 0.0f;
                        } else if (STRIDE == 1 && kw == 2) {
                            v = row[wi >= WIN ? WIN - 1 : wi];
                            if (wi >= WIN) v = 0.0f;
                        } else {
                            v = row[wi];
                        }
                        v *= sc;
#pragma unroll
                        for (int co = 0; co < COB; ++co)
                            acc[p][co] = fmaf(wrow[co], v, acc[p][co]);
                    }
                }
            }
        }
        cur ^= 1;
    }

    float tsum[COB];
#pragma unroll
    for (int co = 0; co < COB; ++co) tsum[co] = 0.0f;
    float* ob = out + (size_t)kk * pstride
              + ((size_t)b * COUT + (size_t)g * COB) * HOUT * WOUT;
#pragma unroll
    for (int p = 0; p < PPT; ++p) {
        const int ho = ty * TH + rg + p * ROWS_T;
#pragma unroll
        for (int co = 0; co < COB; ++co) {
            float v;
            if (BN_RELU)
                v = fmaxf(fmaf(acc[p][co], gl[co], bl[co]), 0.0f);
            else
                v = acc[p][co] + gl[co];
            ob[(size_t)co * HOUT * WOUT + ho * WOUT + wo] = v;
            tsum[co] += v;
        }
    }

    if (SE_SUM) {
#pragma unroll
        for (int co = 0; co < COB; ++co) {
            float v = tsum[co];
            for (int off = 32; off; off >>= 1) v += __shfl_down(v, off, 64);
            if (lane == 0) red[wvid][co] = v;
        }
        __syncthreads();
        if (tid < COB) {
            float v = 0.0f;
#pragma unroll
            for (int k = 0; k < NW; ++k) v += red[k][tid];
            atomicAdd(&se_sum[b * COUT + g * COB + tid], v);
        }
    }
}

// ---------------------------------------------------------------------------
// Combine conv3 partials: h3 = relu((pA+pB)*g*BN_INV + beta), SE3 plane sums.
// One block per (b,c) plane (32x32=1024 px), 256 thr x float4. No atomics.
// ---------------------------------------------------------------------------
__global__ __launch_bounds__(256) void cb_k(const float* __restrict__ pA,
                                            const float* __restrict__ pB,
                                            const float* __restrict__ gamma,
                                            const float* __restrict__ beta,
                                            float* __restrict__ h3,
                                            float* __restrict__ s3)
{
    const int bc = blockIdx.x;       // b*64 + c
    const int c = bc & 63;
    const int tid = threadIdx.x;
    __shared__ float red[4];
    const size_t base = (size_t)bc * 1024;
    float4 a = ((const float4*)(pA + base))[tid];
    float4 d = ((const float4*)(pB + base))[tid];
    const float g = gamma[c] * BN_INV_F, be = beta[c];
    float4 v;
    v.x = fmaxf(fmaf(a.x + d.x, g, be), 0.0f);
    v.y = fmaxf(fmaf(a.y + d.y, g, be), 0.0f);
    v.z = fmaxf(fmaf(a.z + d.z, g, be), 0.0f);
    v.w = fmaxf(fmaf(a.w + d.w, g, be), 0.0f);
    ((float4*)(h3 + base))[tid] = v;
    float s = (v.x + v.y) + (v.z + v.w);
    for (int off = 32; off; off >>= 1) s += __shfl_down(s, off, 64);
    const int lane = tid & 63, wv = tid >> 6;
    if (lane == 0) red[wv] = s;
    __syncthreads();
    if (tid == 0) s3[bc] = (red[0] + red[1]) + (red[2] + red[3]);
}

// ---------------------------------------------------------------------------
__global__ __launch_bounds__(256) void squash4_k(const float* __restrict__ up,
                                                 size_t pstride,
                                                 float* __restrict__ u)
{
    const int idx = blockIdx.x * 256 + threadIdx.x;  // b*2048 + i
    const int b = idx >> 11, i = idx & 2047;
    const int chi = i >> 8, spx = i & 255;
    const size_t off = ((size_t)(b * 64 + chi * 8)) * 256 + spx;
    float s[8];
    float n2 = 0.0f;
#pragma unroll
    for (int j = 0; j < 8; j++) {
        const size_t o = off + (size_t)j * 256;
        s[j] = (up[o] + up[o + pstride]) + (up[o + 2 * pstride] + up[o + 3 * pstride]);
        n2 = fmaf(s[j], s[j], n2);
    }
    const float n = sqrtf(n2);
    const float f = (n2 / (1.0f + n2)) / (n + 1e-8f);
    float* q = u + (size_t)idx * 8;
#pragma unroll
    for (int j = 0; j < 8; j++) q[j] = s[j] * f;
}

// ---------------------------------------------------------------------------
__global__ __launch_bounds__(256) void uhat_k(const float* __restrict__ u,
                                              const float* __restrict__ W,
                                              float* __restrict__ u_hat)
{
    const int idx = blockIdx.x * 256 + threadIdx.x;  // (b*2048+i)*48 + cd
    const int cd = idx % 48;
    const int bi = idx / 48;
    const int i = bi & 2047;
    const float* uu = u + (size_t)bi * 8;
    const float* wp = W + (size_t)i * 384 + cd * 8;
    float a = 0.0f;
#pragma unroll
    for (int e = 0; e < 8; e++) a = fmaf(wp[e], uu[e], a);
    u_hat[idx] = a;
}

// ---------------------------------------------------------------------------
template <int IT>
__global__ __launch_bounds__(256) void sweep_k(const float* __restrict__ u_hat,
                                               const float* __restrict__ s_hist,
                                               float* __restrict__ s_out)
{
    const int b = blockIdx.y;
    const int i = blockIdx.x * 256 + threadIdx.x;
    const int tid = threadIdx.x;
    __shared__ float vsh[IT > 0 ? IT : 1][48];
    __shared__ float fac[IT > 0 ? IT : 1][3];
    __shared__ float red[4][48];

    const float4* qp = (const float4*)(u_hat + ((size_t)b * 2048 + i) * 48);
    float uhv[48];
#pragma unroll
    for (int q = 0; q < 12; ++q) {
        float4 t = qp[q];
        uhv[q * 4 + 0] = t.x; uhv[q * 4 + 1] = t.y;
        uhv[q * 4 + 2] = t.z; uhv[q * 4 + 3] = t.w;
    }

    if (IT > 0) {
        if (tid < IT * 48) {
            int t = tid / 48, c = tid % 48;
            vsh[t][c] = s_hist[((size_t)t * 64 + b) * 48 + c];
        }
        __syncthreads();
        if (tid < IT * 3) {
            int t = tid / 3, j = tid % 3;
            float n2 = 0.0f;
            for (int d = 0; d < 16; ++d) { float s = vsh[t][j * 16 + d]; n2 = fmaf(s, s, n2); }
            float n = sqrtf(n2);
            fac[t][j] = (n2 / (1.0f + n2)) / (n + 1e-8f);
        }
        __syncthreads();
        if (tid < IT * 48) {
            int t = tid / 48, c = tid % 48;
            vsh[t][c] *= fac[t][c / 16];
        }
        __syncthreads();
    }

    float c0, c1, c2;
    if (IT == 0) {
        c0 = c1 = c2 = (1.0f / 3.0f);
    } else {
        float b0 = 0.0f, b1 = 0.0f, b2 = 0.0f;
#pragma unroll
        for (int t = 0; t < IT; ++t)
#pragma unroll
            for (int d = 0; d < 16; ++d) {
                b0 = fmaf(uhv[d],      vsh[t][d],      b0);
                b1 = fmaf(uhv[16 + d], vsh[t][16 + d], b1);
                b2 = fmaf(uhv[32 + d], vsh[t][32 + d], b2);
            }
        float m = fmaxf(b0, fmaxf(b1, b2));
        float e0 = expf(b0 - m), e1 = expf(b1 - m), e2 = expf(b2 - m);
        float inv = 1.0f / (e0 + e1 + e2);
        c0 = e0 * inv; c1 = e1 * inv; c2 = e2 * inv;
    }

    float sp[48];
#pragma unroll
    for (int d = 0; d < 16; ++d) {
        sp[d]      = c0 * uhv[d];
        sp[16 + d] = c1 * uhv[16 + d];
        sp[32 + d] = c2 * uhv[32 + d];
    }
    const int lane = tid & 63, wv = tid >> 6;
#pragma unroll
    for (int j = 0; j < 48; ++j) {
        float x = sp[j];
        for (int off = 32; off; off >>= 1) x += __shfl_down(x, off, 64);
        if (lane == 0) red[wv][j] = x;
    }
    __syncthreads();
    if (tid < 48) {
        float x = red[0][tid] + red[1][tid] + red[2][tid] + red[3][tid];
        atomicAdd(&s_out[(size_t)b * 48 + tid], x);
    }
}

// ---------------------------------------------------------------------------
__global__ __launch_bounds__(64) void route_out_k(const float* __restrict__ s2,
                                                  float* __restrict__ out)
{
    const int b = blockIdx.x;
    __shared__ float s[48];
    if (threadIdx.x < 48) s[threadIdx.x] = s2[(size_t)b * 48 + threadIdx.x];
    __syncthreads();
    if (threadIdx.x < 3) {
        int j = threadIdx.x;
        float n2 = 0.0f;
        for (int d = 0; d < 16; ++d) { float v = s[j * 16 + d]; n2 = fmaf(v, v, n2); }
        float n = sqrtf(n2);
        float fc = (n2 / (1.0f + n2)) / (n + 1e-8f);
        out[b * 3 + j] = fc * n;
    }
}

// ---------------------------------------------------------------------------
extern "C" void kernel_launch(void* const* d_in, const int* in_sizes, int n_in,
                              void* d_out, int out_size, void* d_ws, size_t ws_size,
                              hipStream_t stream)
{
    const float* x       = (const float*)d_in[0];
    const float* conv1_w = (const float*)d_in[1];
    const float* bn1_g   = (const float*)d_in[2];
    const float* bn1_b   = (const float*)d_in[3];
    const float* se1_w1  = (const float*)d_in[4];
    const float* se1_b1  = (const float*)d_in[5];
    const float* se1_w2  = (const float*)d_in[6];
    const float* se1_b2  = (const float*)d_in[7];
    const float* conv2_w = (const float*)d_in[8];
    const float* bn2_g   = (const float*)d_in[9];
    const float* bn2_b   = (const float*)d_in[10];
    const float* se2_w1  = (const float*)d_in[11];
    const float* se2_b1  = (const float*)d_in[12];
    const float* se2_w2  = (const float*)d_in[13];
    const float* se2_b2  = (const float*)d_in[14];
    const float* conv3_w = (const float*)d_in[15];
    const float* bn3_g   = (const float*)d_in[16];
    const float* bn3_b   = (const float*)d_in[17];
    const float* se3_w1  = (const float*)d_in[18];
    const float* se3_b1  = (const float*)d_in[19];
    const float* se3_w2  = (const float*)d_in[20];
    const float* se3_b2  = (const float*)d_in[21];
    const float* pc_w    = (const float*)d_in[22];
    const float* pc_b    = (const float*)d_in[23];
    const float* W_digit = (const float*)d_in[24];  // (1,2048,3,16,8)

    float* ws = (float*)d_ws;
    // float-offset layout (disjoint lifetimes):
    //  [0,16777216)        h1; later h3 overlays [0,4194304)
    //  [4194304,8388608)   conv3 partial cp0 / later pc uparts (4 x 1048576)
    //  [8388608,12582912)  conv3 partial cp1 / later u [8388608,9437184) + u_hat
    //  [9437184,15728640)  u_hat
    //  [16777216,25165824) h2
    //  [25165824,+16448)   SE sums s1/s2/s3 | s_buf | zeros64
    //  [25182272,...)      w1t(144) w2t(4608) w3t(18432) wpt(36864)
    float* h1     = ws;
    float* h2     = ws + 16777216;
    float* h3     = ws;
    float* cp0    = ws + 4194304;
    float* cp1    = ws + 8388608;
    float* uparts = ws + 4194304;
    float* u      = ws + 8388608;
    float* u_hat  = ws + 9437184;
    float* sums   = ws + 25165824;
    float* s1 = sums, *s2 = sums + 1024, *s3 = sums + 3072;
    float* s_buf  = sums + 7168;
    float* zeros64 = sums + 16384;
    float* w1t    = ws + 25182272;
    float* w2t    = w1t + 144;
    float* w3t    = w2t + 4608;
    float* wpt    = w3t + 18432;

    hipMemsetAsync(sums, 0, 16448 * sizeof(float), stream);
    wtrans_all_k<<<235, 256, 0, stream>>>(conv1_w, conv2_w, conv3_w, pc_w,
                                          w1t, w2t, w3t, wpt);

    // conv1: 1->16, 128x128, s1. TW=128, ROWS_T=2, PPT=2 (TH=4), CB=1. 2048 blocks.
    convt_k<1, 1, 16, 16, 128, 128, 1, 128, 2, 2, 1, 256, true, true, 0, 1>
        <<<dim3(32, 1, 64), 256, 0, stream>>>(
            x, w1t, bn1_g, bn1_b, h1, 0, s1,
            nullptr, nullptr, nullptr, nullptr, nullptr, 0.0f);

    // conv2: 16->32, ->64x64, s2. COB=32 (g=1). TW=64, ROWS_T=4, PPT=1, CB=4. 1024 blocks.
    convt_k<16, 16, 32, 32, 128, 64, 2, 64, 4, 1, 4, 256, true, true, 1, 1>
        <<<dim3(16, 1, 64), 256, 0, stream>>>(
            h1, w2t, bn2_g, bn2_b, h2, 0, s2,
            s1, se1_w1, se1_b1, se1_w2, se1_b2, 1.0f / 16384.0f);

    // conv3: 32->64, ->32x32, s2. COB=32 (g=2), KSPLIT=2 (CINB=16), CB=4. 1024 blocks.
    // Raw partials (gamma=zeros64 -> no bias); BN+ReLU+SE3 sums in cb_k.
    convt_k<32, 16, 64, 32, 64, 32, 2, 32, 8, 1, 4, 256, false, false, 2, 2>
        <<<dim3(4, 4, 64), 256, 0, stream>>>(
            h2, w3t, zeros64, nullptr, cp0, (size_t)4194304, nullptr,
            s2, se2_w1, se2_b1, se2_w2, se2_b2, 1.0f / 4096.0f);

    cb_k<<<4096, 256, 0, stream>>>(cp0, cp1, bn3_g, bn3_b, h3, s3);

    // primary caps: 64->64, ->16x16, s2, +bias. COB=16 (g=4), KSPLIT=4 (CINB=16), CB=4. 1024 blocks.
    convt_k<64, 16, 64, 16, 32, 16, 2, 16, 16, 1, 4, 256, false, false, 4, 4>
        <<<dim3(1, 16, 64), 256, 0, stream>>>(
            h3, wpt, pc_b, nullptr, uparts, (size_t)1048576, nullptr,
            s3, se3_w1, se3_b1, se3_w2, se3_b2, 1.0f / 1024.0f);

    squash4_k<<<512, 256, 0, stream>>>(uparts, (size_t)1048576, u);
    uhat_k<<<24576, 256, 0, stream>>>(u, W_digit, u_hat);

    sweep_k<0><<<dim3(8, 64), 256, 0, stream>>>(u_hat, s_buf, s_buf + 0 * 64 * 48);
    sweep_k<1><<<dim3(8, 64), 256, 0, stream>>>(u_hat, s_buf, s_buf + 1 * 64 * 48);
    sweep_k<2><<<dim3(8, 64), 256, 0, stream>>>(u_hat, s_buf, s_buf + 2 * 64 * 48);
    route_out_k<<<64, 64, 0, stream>>>(s_buf + 2 * 64 * 48, (float*)d_out);
}